// Round 8
// baseline (274.526 us; speedup 1.0000x reference)
//
#include <hip/hip_runtime.h>

#define NRES 384
#define CD   128
#define MTOT (NRES*NRES)   /* 147456 */

typedef unsigned short u16;
typedef __bf16 bf16x8 __attribute__((ext_vector_type(8)));
typedef float  f32x16 __attribute__((ext_vector_type(16)));

static __device__ __forceinline__ u16 f2bf(float f) {
  __bf16 b = (__bf16)f;
  return __builtin_bit_cast(u16, b);
}
static __device__ __forceinline__ float bf2f(u16 v) {
  return __uint_as_float(((unsigned)v) << 16);
}
static __device__ __forceinline__ float sigmoidf(float x) {
  // v_exp + v_add + v_rcp: avoids the precise-IEEE div sequence (no fast-math flags)
  return __builtin_amdgcn_rcpf(1.0f + __expf(-x));
}

// async global->LDS, 16B per lane; LDS dest = wave-uniform base + lane*16
static __device__ __forceinline__ void gl16(const void* g, void* l) {
  __builtin_amdgcn_global_load_lds(
      (const __attribute__((address_space(1))) void*)g,
      (__attribute__((address_space(3))) void*)l, 16, 0, 0);
}

// ---------------------------------------------------------------------------
// K0: convert the six 128x128 fp32 weight matrices to bf16 (row-major [n][k])
// order in wb: a_g_w, a_p_w, b_g_w, b_p_w, g_w, z_w' (z_w with ln_out_w folded)
// which-matrix select is BLOCK-uniform (64 blocks per matrix) -> SGPR select.
// ---------------------------------------------------------------------------
__global__ void k_cvt_w(const float* w0, const float* w1, const float* w2,
                        const float* w3, const float* w4, const float* w5,
                        const float* lnw, u16* wb) {
  int i = blockIdx.x * 256 + threadIdx.x;
  int which = blockIdx.x >> 6;   // uniform per block
  const float* src = (which == 0) ? w0 : (which == 1) ? w1 : (which == 2) ? w2
                   : (which == 3) ? w3 : (which == 4) ? w4 : w5;
  float v = src[i & 16383];
  if (which == 5) v *= lnw[i & 127];   // fold ln_out_w into z_w
  wb[i] = f2bf(v);
}

// ---------------------------------------------------------------------------
// K0b: c1[o] = sum_h ln_out_w[h]*z_w[o][h]; c2[o] = sum_h ln_out_b[h]*z_w[o][h] + z_b[o]
// These make LN(x).z_w^T = rs*(x.W'^T) - rs*mu*c1 + c2  (W' = ln_out_w (.) z_w)
// ---------------------------------------------------------------------------
__global__ void k_c12(const float* __restrict__ zw, const float* __restrict__ lnw,
                      const float* __restrict__ lnb, const float* __restrict__ zb,
                      float2* __restrict__ c12) {
  int o = blockIdx.x, l = threadIdx.x;
  float2 v = ((const float2*)(zw + o * CD))[l];
  float2 w = ((const float2*)lnw)[l];
  float2 b = ((const float2*)lnb)[l];
  float s1 = v.x * w.x + v.y * w.y;
  float s2 = v.x * b.x + v.y * b.y;
#pragma unroll
  for (int off = 32; off >= 1; off >>= 1) {
    s1 += __shfl_xor(s1, off);
    s2 += __shfl_xor(s2, off);
  }
  if (l == 0) c12[o] = make_float2(s1, s2 + zb[o]);
}

// ---------------------------------------------------------------------------
// K1: LayerNorm(z) -> zn bf16 [m][c]
// ---------------------------------------------------------------------------
__global__ __launch_bounds__(256) void k_ln_in(const float* __restrict__ z,
                                               const float* __restrict__ w,
                                               const float* __restrict__ b,
                                               u16* __restrict__ zn) {
  int wv = threadIdx.x >> 6, lane = threadIdx.x & 63;
  float2 wv2 = ((const float2*)w)[lane];
  float2 bv2 = ((const float2*)b)[lane];
  for (int rr = 0; rr < 4; ++rr) {
    size_t row = (size_t)blockIdx.x * 16 + wv * 4 + rr;
    float2 v = ((const float2*)(z + row * CD))[lane];
    float s = v.x + v.y;
#pragma unroll
    for (int off = 32; off >= 1; off >>= 1) s += __shfl_xor(s, off);
    float mu = s * (1.0f / CD);
    float dx = v.x - mu, dy = v.y - mu;
    float vr = dx * dx + dy * dy;
#pragma unroll
    for (int off = 32; off >= 1; off >>= 1) vr += __shfl_xor(vr, off);
    float rs = rsqrtf(vr * (1.0f / CD) + 1e-5f);
    ushort2 o;
    o.x = f2bf(dx * rs * wv2.x + bv2.x);
    o.y = f2bf(dy * rs * wv2.y + bv2.y);
    ((ushort2*)(zn + row * CD))[lane] = o;
  }
}

// ---------------------------------------------------------------------------
// K2: a/b projections off zn. Type-split grid (576,2); 4x64-row subtiles,
// TWO LDS buffers (33KB -> 4 blocks/CU, was 3@50KB), depth-2 prefetch,
// raw s_barrier + EXACT counted vmcnt (T3/T4). A second, drain-free barrier
// after each compute+stores guards the buffer before it is re-staged.
// Count derivation (vmcnt retires in issue order; fences pin op positions;
// u16 stores to non-adjacent addresses cannot merge or split):
//   iter0 awaits G0: younger = G1(4)                  -> vmcnt(4)
//   iter1 awaits G1: younger = stores0(32) + G2(4)    -> vmcnt(36)
//   iter2 awaits G2: younger = stores1(32) + G3(4)    -> vmcnt(36)
//   iter3 awaits G3: younger = stores2(32)            -> vmcnt(32)
// Counts proven on HW in R5/R6. LDS 16-slot XOR swizzle (conflict-free, R6).
// ---------------------------------------------------------------------------
__global__ __launch_bounds__(256) void k_proj(
    const u16* __restrict__ zn, const float* __restrict__ mask,
    const u16* __restrict__ wb,
    const float* __restrict__ agb, const float* __restrict__ apb,
    const float* __restrict__ bgb, const float* __restrict__ bpb,
    u16* __restrict__ a_out, u16* __restrict__ b_out) {
  int type = blockIdx.y;
  int m_base = blockIdx.x * 256;
  int t = threadIdx.x;
  int lane = t & 63;
  int wvu = __builtin_amdgcn_readfirstlane(t >> 6);
  int nl = lane & 31, s = lane >> 5;
  int h = wvu * 32 + nl;

  const u16* wgp = wb + (size_t)type * 32768;
  const u16* wpp = wgp + 16384;
  const float* bgp = (type == 0) ? agb : bgb;
  const float* bpp = (type == 0) ? apb : bpb;
  u16* outp = (type == 0) ? a_out : b_out;

  __shared__ u16 znt[2][64][128];   // 32 KB, 16-slot swizzled
  __shared__ float bsl[2][128];     // biases (gate, proj)

  if (t < 128) bsl[0][t] = bgp[t];
  else         bsl[1][t - 128] = bpp[t - 128];

  float mk0[4], mk1[4];
#pragma unroll
  for (int ms = 0; ms < 4; ++ms) {
    mk0[ms] = mask[m_base + ms * 64 + nl];
    mk1[ms] = mask[m_base + ms * 64 + 32 + nl];
  }

  bf16x8 wgf[8], wpf[8];
#pragma unroll
  for (int kk = 0; kk < 8; ++kk) {
    wgf[kk] = *(const bf16x8*)(wgp + h * CD + kk * 16 + s * 8);
    wpf[kk] = *(const bf16x8*)(wpp + h * CD + kk * 16 + s * 8);
  }

  int rl = lane >> 4, p16 = lane & 15;
#define STAGE_ZNT(mt, bf)                                                   \
  {                                                                         \
    _Pragma("unroll")                                                       \
    for (int j = 0; j < 4; ++j) {                                           \
      int row = wvu * 16 + j * 4 + rl;                                      \
      int gc = (p16 ^ (row & 15)) << 3;                                     \
      gl16(zn + (size_t)((mt) + row) * CD + gc, &znt[bf][wvu * 16 + j * 4][0]); \
    }                                                                       \
  }

  asm volatile("" ::: "memory");
  STAGE_ZNT(m_base, 0);          // G0
  asm volatile("" ::: "memory");
  STAGE_ZNT(m_base + 64, 1);     // G1
  asm volatile("" ::: "memory");

  asm volatile("s_waitcnt lgkmcnt(0)" ::: "memory");  // bias ds_writes done

#define PROJ_ITER(ms, buf, WAITINSN, STAGEIT)                                 \
  {                                                                           \
    asm volatile(WAITINSN ::: "memory");                                      \
    __builtin_amdgcn_s_barrier();                                             \
    asm volatile("" ::: "memory");                                            \
    f32x16 accg0, accg1, accp0, accp1;                                        \
    _Pragma("unroll")                                                         \
    for (int i = 0; i < 16; ++i) {                                            \
      accg0[i] = 0; accg1[i] = 0; accp0[i] = 0; accp1[i] = 0;                 \
    }                                                                         \
    _Pragma("unroll")                                                         \
    for (int kk = 0; kk < 8; ++kk) {                                          \
      int c = ((kk * 2 + s) ^ (nl & 15)) << 3;                                \
      bf16x8 zf0 = *(const bf16x8*)&znt[buf][nl][c];                          \
      bf16x8 zf1 = *(const bf16x8*)&znt[buf][32 + nl][c];                     \
      accg0 = __builtin_amdgcn_mfma_f32_32x32x16_bf16(wgf[kk], zf0, accg0, 0, 0, 0); \
      accg1 = __builtin_amdgcn_mfma_f32_32x32x16_bf16(wgf[kk], zf1, accg1, 0, 0, 0); \
      accp0 = __builtin_amdgcn_mfma_f32_32x32x16_bf16(wpf[kk], zf0, accp0, 0, 0, 0); \
      accp1 = __builtin_amdgcn_mfma_f32_32x32x16_bf16(wpf[kk], zf1, accp1, 0, 0, 0); \
    }                                                                         \
    int mt = m_base + (ms) * 64;                                              \
    _Pragma("unroll")                                                         \
    for (int r = 0; r < 16; ++r) {                                            \
      int hh = wvu * 32 + (r & 3) + 8 * (r >> 2) + 4 * s;                     \
      float bg = bsl[0][hh], bp = bsl[1][hh];                                 \
      u16* rowp = outp + (size_t)hh * MTOT + mt + nl;                         \
      rowp[0]  = f2bf(mk0[ms] * sigmoidf(accg0[r] + bg) * (accp0[r] + bp));   \
      rowp[32] = f2bf(mk1[ms] * sigmoidf(accg1[r] + bg) * (accp1[r] + bp));   \
    }                                                                         \
    asm volatile("" ::: "memory");                                            \
    if (STAGEIT) {                                                            \
      __builtin_amdgcn_s_barrier();   /* buffer reads done; drain-free */     \
      asm volatile("" ::: "memory");                                          \
      STAGE_ZNT(m_base + ((ms) + 2) * 64, buf);                               \
      asm volatile("" ::: "memory");                                          \
    }                                                                         \
  }

  PROJ_ITER(0, 0, "s_waitcnt vmcnt(4)",  1);   // awaits G0; G1 in flight; G2->b0
  PROJ_ITER(1, 1, "s_waitcnt vmcnt(36)", 1);   // awaits G1; stores0+G2 in flight; G3->b1
  PROJ_ITER(2, 0, "s_waitcnt vmcnt(36)", 0);   // awaits G2; stores1+G3 in flight
  PROJ_ITER(3, 1, "s_waitcnt vmcnt(32)", 0);   // awaits G3; stores2 in flight
#undef PROJ_ITER
#undef STAGE_ZNT
}

// ---------------------------------------------------------------------------
// K3: triangle einsum. Per channel h: X_h = A_h * B_h^T (bf16 NT).
// 128x128 tile, BK=64. T3/T4 conversion: raw s_barrier + counted vmcnt;
// prologue stages G0,G1; each K-step waits ONLY its own stage (the next
// stage's 8 gl16 stay in flight across both barriers -- no mid-loop drain).
// Buffer rotation: compute b(kb&1), then after a drain-free barrier restage
// G_{kb+2} into that same buffer. No stores mid-loop -> counts exact: 8/0.
// XCD-aware remap (T1): each XCD gets 16 whole channels x 9 tiles; A_h+B_h
// (590KB) fits its 4MB L2 so the 3x panel re-reads hit L2.
// ---------------------------------------------------------------------------
__global__ __launch_bounds__(256) void k_tri(const u16* __restrict__ a,
                                             const u16* __restrict__ b,
                                             u16* __restrict__ x) {
  int n = blockIdx.x;
  int w = (n & 7) * 144 + (n >> 3);   // 1152 = 8 XCDs * 144
  int h = w / 9;
  int tile = w % 9;
  int tm = tile / 3, tn = tile % 3;
  int i0 = tm * 128, j0 = tn * 128;
  const u16* ah = a + (size_t)h * MTOT;
  const u16* bh = b + (size_t)h * MTOT;

  __shared__ u16 At[2][128][64];
  __shared__ u16 Bt[2][128][64];

  int lane = threadIdx.x & 63;
  int wvu = __builtin_amdgcn_readfirstlane(threadIdx.x >> 6);
  int nl = lane & 31, s = lane >> 5;
  int wr = wvu >> 1, wc = wvu & 1;
  int rl = lane >> 3, p8 = lane & 7;

  f32x16 acc[4];
#pragma unroll
  for (int q = 0; q < 4; ++q)
#pragma unroll
    for (int i = 0; i < 16; ++i) acc[q][i] = 0;

#define STAGE_TRI(bf, k0)                                                     \
  {                                                                           \
    _Pragma("unroll")                                                         \
    for (int j = 0; j < 4; ++j) {                                             \
      int row = wvu * 32 + j * 8 + rl;                                        \
      int gc = (p8 ^ (rl & 7)) << 3;                                          \
      gl16(ah + (size_t)(i0 + row) * NRES + (k0) + gc, &At[bf][wvu * 32 + j * 8][0]); \
      gl16(bh + (size_t)(j0 + row) * NRES + (k0) + gc, &Bt[bf][wvu * 32 + j * 8][0]); \
    }                                                                         \
  }

  asm volatile("" ::: "memory");
  STAGE_TRI(0, 0);        // G0 -> b0
  asm volatile("" ::: "memory");
  STAGE_TRI(1, 64);       // G1 -> b1
  asm volatile("" ::: "memory");

#define TRI_ITER(kb, WAITINSN, STAGEIT)                                       \
  {                                                                           \
    const int cur = (kb) & 1;                                                 \
    asm volatile(WAITINSN ::: "memory");                                      \
    __builtin_amdgcn_s_barrier();                                             \
    asm volatile("" ::: "memory");                                            \
    _Pragma("unroll")                                                         \
    for (int kk = 0; kk < 4; ++kk) {                                          \
      int c = ((kk * 2 + s) ^ (nl & 7)) << 3;                                 \
      bf16x8 af0 = *(const bf16x8*)&At[cur][wr * 64 + nl][c];                 \
      bf16x8 af1 = *(const bf16x8*)&At[cur][wr * 64 + 32 + nl][c];            \
      bf16x8 bf0 = *(const bf16x8*)&Bt[cur][wc * 64 + nl][c];                 \
      bf16x8 bf1 = *(const bf16x8*)&Bt[cur][wc * 64 + 32 + nl][c];            \
      acc[0] = __builtin_amdgcn_mfma_f32_32x32x16_bf16(af0, bf0, acc[0], 0, 0, 0); \
      acc[1] = __builtin_amdgcn_mfma_f32_32x32x16_bf16(af0, bf1, acc[1], 0, 0, 0); \
      acc[2] = __builtin_amdgcn_mfma_f32_32x32x16_bf16(af1, bf0, acc[2], 0, 0, 0); \
      acc[3] = __builtin_amdgcn_mfma_f32_32x32x16_bf16(af1, bf1, acc[3], 0, 0, 0); \
    }                                                                         \
    asm volatile("s_waitcnt lgkmcnt(0)" ::: "memory");                        \
    if (STAGEIT) {                                                            \
      __builtin_amdgcn_s_barrier();   /* buffer reads done; drain-free */     \
      asm volatile("" ::: "memory");                                          \
      STAGE_TRI(cur, ((kb) + 2) * 64);                                        \
      asm volatile("" ::: "memory");                                          \
    }                                                                         \
  }

  TRI_ITER(0, "s_waitcnt vmcnt(8)", 1);   // awaits G0; G1 in flight; G2->b0
  TRI_ITER(1, "s_waitcnt vmcnt(8)", 1);   // awaits G1; G2 in flight; G3->b1
  TRI_ITER(2, "s_waitcnt vmcnt(8)", 1);   // awaits G2; G3 in flight; G4->b0
  TRI_ITER(3, "s_waitcnt vmcnt(8)", 1);   // awaits G3; G4 in flight; G5->b1
  TRI_ITER(4, "s_waitcnt vmcnt(8)", 0);   // awaits G4; G5 in flight
  TRI_ITER(5, "s_waitcnt vmcnt(0)", 0);   // awaits G5 (last)
#undef TRI_ITER
#undef STAGE_TRI

  u16* xh = x + (size_t)h * MTOT;
#pragma unroll
  for (int msub = 0; msub < 2; ++msub)
#pragma unroll
    for (int nsub = 0; nsub < 2; ++nsub) {
      int j = j0 + wc * 64 + nsub * 32 + nl;
#pragma unroll
      for (int r = 0; r < 16; ++r) {
        int i = i0 + wr * 64 + msub * 32 + (r & 3) + 8 * (r >> 2) + 4 * s;
        xh[(size_t)i * NRES + j] = f2bf(acc[msub * 2 + nsub][r]);
      }
    }
}

// ---------------------------------------------------------------------------
// K4: out[m][o] = sigmoid(zn.g_w^T + g_b)[m][o]
//               * ( rs[m]*(x.W'^T)[m][o] - rs[m]*mu[m]*c1[o] + c2[o] )
// LN folded algebraically (W' = ln_out_w (.) z_w, c1/c2 precomputed):
// no normalize write-back pass, GEMM runs on the RAW transposed x tile.
// Load-order discipline: zn loads -> gwf/gb -> x prefetch; lgkm-only raw
// barriers. vmcnt retires in order, so the zn/gwf waits never drain the
// younger x loads -> x HBM latency hides under the gate GEMM (T14).
// ---------------------------------------------------------------------------
__global__ __launch_bounds__(256) void k_out(
    const u16* __restrict__ x, const u16* __restrict__ zn,
    const u16* __restrict__ wb, const float* __restrict__ gb,
    const float2* __restrict__ c12, float* __restrict__ out) {
  int m0 = blockIdx.x * 64;
  int t = threadIdx.x;
  int wv = t >> 6, lane = t & 63, nl = lane & 31, s = lane >> 5;
  int o = wv * 32 + nl;

  __shared__ u16 tile[64][136];
  __shared__ float2 stat[64];   // {rs, rs*mu} per m-row

  const u16* gwp = wb + 4 * 16384;   // g_w
  const u16* zwp = wb + 5 * 16384;   // W' = z_w with ln_out_w folded

  // ---- issue order: zn(oldest) -> gwf,gb -> x(youngest)
  uint4 znv[4];
#pragma unroll
  for (int it = 0; it < 4; ++it) {
    int idx = it * 256 + t, r = idx >> 4, c8 = idx & 15;
    znv[it] = *(const uint4*)(zn + (size_t)(m0 + r) * CD + c8 * 8);
  }
  bf16x8 gwf[8];
#pragma unroll
  for (int kk = 0; kk < 8; ++kk)
    gwf[kk] = *(const bf16x8*)(gwp + o * CD + kk * 16 + s * 8);
  float gbv = gb[o];

  int mc = t & 7;
  uint4 xv0[2], xv1[2];
#pragma unroll
  for (int ps = 0; ps < 2; ++ps) {
    int hp = (ps * 256 + t) >> 3;
    xv0[ps] = *(const uint4*)(x + (size_t)(2 * hp)     * MTOT + m0 + mc * 8);
    xv1[ps] = *(const uint4*)(x + (size_t)(2 * hp + 1) * MTOT + m0 + mc * 8);
  }

  // stage zn -> tile (waits only zn; x stays in flight)
#pragma unroll
  for (int it = 0; it < 4; ++it) {
    int idx = it * 256 + t, r = idx >> 4, c8 = idx & 15;
    *(uint4*)&tile[r][c8 * 8] = znv[it];
  }
  asm volatile("s_waitcnt lgkmcnt(0)" ::: "memory");
  __builtin_amdgcn_s_barrier();

  // ---- phase A: gate GEMM (C[m][o])
  f32x16 gacc[2];
#pragma unroll
  for (int i = 0; i < 16; ++i) { gacc[0][i] = 0; gacc[1][i] = 0; }
#pragma unroll
  for (int kk = 0; kk < 8; ++kk) {
    bf16x8 zf0 = *(const bf16x8*)&tile[nl][kk * 16 + s * 8];
    bf16x8 zf1 = *(const bf16x8*)&tile[32 + nl][kk * 16 + s * 8];
    gacc[0] = __builtin_amdgcn_mfma_f32_32x32x16_bf16(zf0, gwf[kk], gacc[0], 0, 0, 0);
    gacc[1] = __builtin_amdgcn_mfma_f32_32x32x16_bf16(zf1, gwf[kk], gacc[1], 0, 0, 0);
  }
  float gv[32];
#pragma unroll
  for (int ms = 0; ms < 2; ++ms)
#pragma unroll
    for (int r = 0; r < 16; ++r)
      gv[ms * 16 + r] = sigmoidf(gacc[ms][r] + gbv);
  asm volatile("s_waitcnt lgkmcnt(0)" ::: "memory");
  __builtin_amdgcn_s_barrier();   // all waves done reading zn tile

  // W' fragments (younger than x; x-waits below don't drain these)
  bf16x8 zwf[8];
#pragma unroll
  for (int kk = 0; kk < 8; ++kk)
    zwf[kk] = *(const bf16x8*)(zwp + o * CD + kk * 16 + s * 8);

  // ---- phase B: transpose x[h][m] -> tile[m][h] (consumes prefetched regs)
#pragma unroll
  for (int ps = 0; ps < 2; ++ps) {
    int hp = (ps * 256 + t) >> 3;
    unsigned c0[4] = {xv0[ps].x, xv0[ps].y, xv0[ps].z, xv0[ps].w};
    unsigned c1[4] = {xv1[ps].x, xv1[ps].y, xv1[ps].z, xv1[ps].w};
#pragma unroll
    for (int q = 0; q < 4; ++q) {
      ushort2 lo, hi;
      lo.x = (u16)(c0[q] & 0xffffu); lo.y = (u16)(c1[q] & 0xffffu);
      hi.x = (u16)(c0[q] >> 16);     hi.y = (u16)(c1[q] >> 16);
      *(ushort2*)&tile[mc * 8 + 2 * q][2 * hp]     = lo;
      *(ushort2*)&tile[mc * 8 + 2 * q + 1][2 * hp] = hi;
    }
  }
  asm volatile("s_waitcnt lgkmcnt(0)" ::: "memory");
  __builtin_amdgcn_s_barrier();

  // ---- stats: one-pass mean/var per m-row (4x b128 reads, no write-back)
  {
    int r = t >> 2, q = t & 3;
    float sum = 0.0f, sq = 0.0f;
#pragma unroll
    for (int i = 0; i < 4; ++i) {
      uint4 v = *(const uint4*)&tile[r][q * 32 + i * 8];
      unsigned cc[4] = {v.x, v.y, v.z, v.w};
#pragma unroll
      for (int j = 0; j < 4; ++j) {
        float a = bf2f((u16)(cc[j] & 0xffffu));
        float b = bf2f((u16)(cc[j] >> 16));
        sum += a + b; sq += a * a + b * b;
      }
    }
    sum += __shfl_xor(sum, 1); sum += __shfl_xor(sum, 2);
    sq  += __shfl_xor(sq, 1);  sq  += __shfl_xor(sq, 2);
    float mu = sum * (1.0f / CD);
    float var = sq * (1.0f / CD) - mu * mu;
    float rs = rsqrtf(var + 1e-5f);
    if (q == 0) stat[r] = make_float2(rs, rs * mu);
  }

  // ---- W' GEMM on the raw x tile (reads only; no barrier needed vs stats)
  f32x16 acc[2];
#pragma unroll
  for (int i = 0; i < 16; ++i) { acc[0][i] = 0; acc[1][i] = 0; }
#pragma unroll
  for (int kk = 0; kk < 8; ++kk) {
    bf16x8 af0 = *(const bf16x8*)&tile[nl][kk * 16 + s * 8];
    bf16x8 af1 = *(const bf16x8*)&tile[32 + nl][kk * 16 + s * 8];
    acc[0] = __builtin_amdgcn_mfma_f32_32x32x16_bf16(af0, zwf[kk], acc[0], 0, 0, 0);
    acc[1] = __builtin_amdgcn_mfma_f32_32x32x16_bf16(af1, zwf[kk], acc[1], 0, 0, 0);
  }
  asm volatile("s_waitcnt lgkmcnt(0)" ::: "memory");
  __builtin_amdgcn_s_barrier();   // stat[] visible to all

  float2 cc2 = c12[o];
#pragma unroll
  for (int ms = 0; ms < 2; ++ms)
#pragma unroll
    for (int rr = 0; rr < 16; ++rr) {
      int rowoff = (rr & 3) + 8 * (rr >> 2) + 4 * s;
      int row = ms * 32 + rowoff;
      float2 st = stat[row];
      out[(size_t)(m0 + row) * CD + o] =
          gv[ms * 16 + rr] * (st.x * acc[ms][rr] - st.y * cc2.x + cc2.y);
    }
}

// ---------------------------------------------------------------------------
extern "C" void kernel_launch(void* const* d_in, const int* in_sizes, int n_in,
                              void* d_out, int out_size, void* d_ws, size_t ws_size,
                              hipStream_t stream) {
  const float* z       = (const float*)d_in[0];
  const float* mask    = (const float*)d_in[1];
  const float* ln_in_w = (const float*)d_in[2];
  const float* ln_in_b = (const float*)d_in[3];
  const float* a_g_w   = (const float*)d_in[4];
  const float* a_g_b   = (const float*)d_in[5];
  const float* a_p_w   = (const float*)d_in[6];
  const float* a_p_b   = (const float*)d_in[7];
  const float* b_g_w   = (const float*)d_in[8];
  const float* b_g_b   = (const float*)d_in[9];
  const float* b_p_w   = (const float*)d_in[10];
  const float* b_p_b   = (const float*)d_in[11];
  const float* g_w     = (const float*)d_in[12];
  const float* g_b     = (const float*)d_in[13];
  const float* ln_o_w  = (const float*)d_in[14];
  const float* ln_o_b  = (const float*)d_in[15];
  const float* z_w     = (const float*)d_in[16];
  const float* z_b     = (const float*)d_in[17];
  float* out = (float*)d_out;

  const size_t SZ = (size_t)MTOT * CD * sizeof(u16);
  char* w = (char*)d_ws;
  u16* zn = (u16*)(w);              // live until k_out
  u16* a  = (u16*)(w + SZ);
  u16* b  = (u16*)(w + 2 * SZ);
  u16* x  = (u16*)(w + 3 * SZ);
  u16* wb = (u16*)(w + 4 * SZ);
  float2* c12 = (float2*)(w + 4 * SZ + 6 * 16384 * sizeof(u16));
  (void)ws_size; (void)in_sizes; (void)n_in; (void)out_size;

  k_cvt_w<<<384, 256, 0, stream>>>(a_g_w, a_p_w, b_g_w, b_p_w, g_w, z_w,
                                   ln_o_w, wb);
  k_c12<<<128, 64, 0, stream>>>(z_w, ln_o_w, ln_o_b, z_b, c12);
  k_ln_in<<<MTOT / 16, 256, 0, stream>>>(z, ln_in_w, ln_in_b, zn);
  k_proj<<<dim3(MTOT / 256, 2), 256, 0, stream>>>(zn, mask, wb,
      a_g_b, a_p_b, b_g_b, b_p_b, a, b);
  k_tri<<<1152, 256, 0, stream>>>(a, b, x);
  k_out<<<MTOT / 64, 256, 0, stream>>>(x, zn, wb, g_b, c12, out);
}

// Round 9
// 270.138 us; speedup vs baseline: 1.0162x; 1.0162x over previous
//
#include <hip/hip_runtime.h>

#define NRES 384
#define CD   128
#define MTOT (NRES*NRES)   /* 147456 */

typedef unsigned short u16;
typedef __bf16 bf16x8 __attribute__((ext_vector_type(8)));
typedef float  f32x16 __attribute__((ext_vector_type(16)));

static __device__ __forceinline__ u16 f2bf(float f) {
  __bf16 b = (__bf16)f;
  return __builtin_bit_cast(u16, b);
}
static __device__ __forceinline__ float bf2f(u16 v) {
  return __uint_as_float(((unsigned)v) << 16);
}
static __device__ __forceinline__ float sigmoidf(float x) {
  // v_exp + v_add + v_rcp: avoids the precise-IEEE div sequence (no fast-math flags)
  return __builtin_amdgcn_rcpf(1.0f + __expf(-x));
}

// async global->LDS, 16B per lane; LDS dest = wave-uniform base + lane*16
static __device__ __forceinline__ void gl16(const void* g, void* l) {
  __builtin_amdgcn_global_load_lds(
      (const __attribute__((address_space(1))) void*)g,
      (__attribute__((address_space(3))) void*)l, 16, 0, 0);
}

// ---------------------------------------------------------------------------
// K0: convert the six 128x128 fp32 weight matrices to bf16 (row-major [n][k])
// order in wb: a_g_w, a_p_w, b_g_w, b_p_w, g_w, z_w' (z_w with ln_out_w folded)
// which-matrix select is BLOCK-uniform (64 blocks per matrix) -> SGPR select.
// ---------------------------------------------------------------------------
__global__ void k_cvt_w(const float* w0, const float* w1, const float* w2,
                        const float* w3, const float* w4, const float* w5,
                        const float* lnw, u16* wb) {
  int i = blockIdx.x * 256 + threadIdx.x;
  int which = blockIdx.x >> 6;   // uniform per block
  const float* src = (which == 0) ? w0 : (which == 1) ? w1 : (which == 2) ? w2
                   : (which == 3) ? w3 : (which == 4) ? w4 : w5;
  float v = src[i & 16383];
  if (which == 5) v *= lnw[i & 127];   // fold ln_out_w into z_w
  wb[i] = f2bf(v);
}

// ---------------------------------------------------------------------------
// K0b: c1[o] = sum_h ln_out_w[h]*z_w[o][h]; c2[o] = sum_h ln_out_b[h]*z_w[o][h] + z_b[o]
// These make LN(x).z_w^T = rs*(x.W'^T) - rs*mu*c1 + c2  (W' = ln_out_w (.) z_w)
// ---------------------------------------------------------------------------
__global__ void k_c12(const float* __restrict__ zw, const float* __restrict__ lnw,
                      const float* __restrict__ lnb, const float* __restrict__ zb,
                      float2* __restrict__ c12) {
  int o = blockIdx.x, l = threadIdx.x;
  float2 v = ((const float2*)(zw + o * CD))[l];
  float2 w = ((const float2*)lnw)[l];
  float2 b = ((const float2*)lnb)[l];
  float s1 = v.x * w.x + v.y * w.y;
  float s2 = v.x * b.x + v.y * b.y;
#pragma unroll
  for (int off = 32; off >= 1; off >>= 1) {
    s1 += __shfl_xor(s1, off);
    s2 += __shfl_xor(s2, off);
  }
  if (l == 0) c12[o] = make_float2(s1, s2 + zb[o]);
}

// ---------------------------------------------------------------------------
// K1: LayerNorm(z) -> zn bf16 [m][c]. G13-compliant rewrite:
// float4 loads (16B/lane), 2 rows per wave via 32-lane groups (5 shfl
// rounds, offsets<32 stay within each half-wave), ushort4 stores (8B/lane).
// Each wave: 8 rows (4 unrolled passes x 2); block = 32 rows; grid MTOT/32.
// ---------------------------------------------------------------------------
__global__ __launch_bounds__(256) void k_ln_in(const float* __restrict__ z,
                                               const float* __restrict__ w,
                                               const float* __restrict__ b,
                                               u16* __restrict__ zn) {
  int wv = threadIdx.x >> 6, lane = threadIdx.x & 63;
  int s = lane >> 5, l32 = lane & 31;
  float4 wv4 = ((const float4*)w)[l32];
  float4 bv4 = ((const float4*)b)[l32];
#pragma unroll
  for (int rr = 0; rr < 4; ++rr) {
    size_t row = (size_t)blockIdx.x * 32 + wv * 8 + rr * 2 + s;
    float4 v = ((const float4*)(z + row * CD))[l32];
    float sm = v.x + v.y + v.z + v.w;
#pragma unroll
    for (int off = 16; off >= 1; off >>= 1) sm += __shfl_xor(sm, off);
    float mu = sm * (1.0f / CD);
    float dx = v.x - mu, dy = v.y - mu, dz = v.z - mu, dw = v.w - mu;
    float vr = dx * dx + dy * dy + dz * dz + dw * dw;
#pragma unroll
    for (int off = 16; off >= 1; off >>= 1) vr += __shfl_xor(vr, off);
    float rs = rsqrtf(vr * (1.0f / CD) + 1e-5f);
    ushort4 o;
    o.x = f2bf(dx * rs * wv4.x + bv4.x);
    o.y = f2bf(dy * rs * wv4.y + bv4.y);
    o.z = f2bf(dz * rs * wv4.z + bv4.z);
    o.w = f2bf(dw * rs * wv4.w + bv4.w);
    ((ushort4*)(zn + row * CD))[l32] = o;
  }
}

// ---------------------------------------------------------------------------
// K2: a/b projections off zn. REVERTED to the R6 HW-proven form (R8's
// 2-buffer variant regressed: VGPR 104->136, occupancy 16->9%, dur 47->62).
// Type-split grid (576,2); 4x64-row subtiles, THREE LDS buffers, depth-2
// prefetch, raw s_barrier + EXACT counted vmcnt (T3/T4):
//   iter0 awaits G0: younger = G1(4)                  -> vmcnt(4)
//   iter1 awaits G1: younger = stores0(32) + G2(4)    -> vmcnt(36)
//   iter2 awaits G2: younger = stores1(32) + G3(4)    -> vmcnt(36)
//   iter3 awaits G3: younger = stores2(32)            -> vmcnt(32)
// LDS 16-slot XOR swizzle (bank-conflict-free, verified 1.18M -> 0 in R6).
// ---------------------------------------------------------------------------
__global__ __launch_bounds__(256) void k_proj(
    const u16* __restrict__ zn, const float* __restrict__ mask,
    const u16* __restrict__ wb,
    const float* __restrict__ agb, const float* __restrict__ apb,
    const float* __restrict__ bgb, const float* __restrict__ bpb,
    u16* __restrict__ a_out, u16* __restrict__ b_out) {
  int type = blockIdx.y;
  int m_base = blockIdx.x * 256;
  int t = threadIdx.x;
  int lane = t & 63;
  int wvu = __builtin_amdgcn_readfirstlane(t >> 6);
  int nl = lane & 31, s = lane >> 5;
  int h = wvu * 32 + nl;

  const u16* wgp = wb + (size_t)type * 32768;
  const u16* wpp = wgp + 16384;
  const float* bgp = (type == 0) ? agb : bgb;
  const float* bpp = (type == 0) ? apb : bpb;
  u16* outp = (type == 0) ? a_out : b_out;

  __shared__ u16 znt[3][64][128];   // 48 KB, 16-slot swizzled
  __shared__ float bsl[2][128];     // biases (gate, proj)

  if (t < 128) bsl[0][t] = bgp[t];
  else         bsl[1][t - 128] = bpp[t - 128];

  float mk0[4], mk1[4];
#pragma unroll
  for (int ms = 0; ms < 4; ++ms) {
    mk0[ms] = mask[m_base + ms * 64 + nl];
    mk1[ms] = mask[m_base + ms * 64 + 32 + nl];
  }

  bf16x8 wgf[8], wpf[8];
#pragma unroll
  for (int kk = 0; kk < 8; ++kk) {
    wgf[kk] = *(const bf16x8*)(wgp + h * CD + kk * 16 + s * 8);
    wpf[kk] = *(const bf16x8*)(wpp + h * CD + kk * 16 + s * 8);
  }

  int rl = lane >> 4, p16 = lane & 15;
#define STAGE_ZNT(mt, bf)                                                   \
  {                                                                         \
    _Pragma("unroll")                                                       \
    for (int j = 0; j < 4; ++j) {                                           \
      int row = wvu * 16 + j * 4 + rl;                                      \
      int gc = (p16 ^ (row & 15)) << 3;                                     \
      gl16(zn + (size_t)((mt) + row) * CD + gc, &znt[bf][wvu * 16 + j * 4][0]); \
    }                                                                       \
  }

  asm volatile("" ::: "memory");
  STAGE_ZNT(m_base, 0);          // G0
  asm volatile("" ::: "memory");
  STAGE_ZNT(m_base + 64, 1);     // G1
  asm volatile("" ::: "memory");

  asm volatile("s_waitcnt lgkmcnt(0)" ::: "memory");  // bias ds_writes done

#define PROJ_ITER(ms, buf, WAITINSN, STAGEIT, stbuf)                          \
  {                                                                           \
    asm volatile(WAITINSN ::: "memory");                                      \
    __builtin_amdgcn_s_barrier();                                             \
    asm volatile("" ::: "memory");                                            \
    f32x16 accg0, accg1, accp0, accp1;                                        \
    _Pragma("unroll")                                                         \
    for (int i = 0; i < 16; ++i) {                                            \
      accg0[i] = 0; accg1[i] = 0; accp0[i] = 0; accp1[i] = 0;                 \
    }                                                                         \
    _Pragma("unroll")                                                         \
    for (int kk = 0; kk < 8; ++kk) {                                          \
      int c = ((kk * 2 + s) ^ (nl & 15)) << 3;                                \
      bf16x8 zf0 = *(const bf16x8*)&znt[buf][nl][c];                          \
      bf16x8 zf1 = *(const bf16x8*)&znt[buf][32 + nl][c];                     \
      accg0 = __builtin_amdgcn_mfma_f32_32x32x16_bf16(wgf[kk], zf0, accg0, 0, 0, 0); \
      accg1 = __builtin_amdgcn_mfma_f32_32x32x16_bf16(wgf[kk], zf1, accg1, 0, 0, 0); \
      accp0 = __builtin_amdgcn_mfma_f32_32x32x16_bf16(wpf[kk], zf0, accp0, 0, 0, 0); \
      accp1 = __builtin_amdgcn_mfma_f32_32x32x16_bf16(wpf[kk], zf1, accp1, 0, 0, 0); \
    }                                                                         \
    int mt = m_base + (ms) * 64;                                              \
    _Pragma("unroll")                                                         \
    for (int r = 0; r < 16; ++r) {                                            \
      int hh = wvu * 32 + (r & 3) + 8 * (r >> 2) + 4 * s;                     \
      float bg = bsl[0][hh], bp = bsl[1][hh];                                 \
      u16* rowp = outp + (size_t)hh * MTOT + mt + nl;                         \
      rowp[0]  = f2bf(mk0[ms] * sigmoidf(accg0[r] + bg) * (accp0[r] + bp));   \
      rowp[32] = f2bf(mk1[ms] * sigmoidf(accg1[r] + bg) * (accp1[r] + bp));   \
    }                                                                         \
    asm volatile("" ::: "memory");                                            \
    if (STAGEIT) STAGE_ZNT(m_base + ((ms) + 2) * 64, stbuf);                  \
    asm volatile("" ::: "memory");                                            \
  }

  PROJ_ITER(0, 0, "s_waitcnt vmcnt(4)",  1, 2);   // awaits G0; G1 in flight; G2->b2
  PROJ_ITER(1, 1, "s_waitcnt vmcnt(36)", 1, 0);   // awaits G1; stores0+G2 in flight; G3->b0
  PROJ_ITER(2, 2, "s_waitcnt vmcnt(36)", 0, 0);   // awaits G2; stores1+G3 in flight
  PROJ_ITER(3, 0, "s_waitcnt vmcnt(32)", 0, 0);   // awaits G3; stores2 in flight
#undef PROJ_ITER
#undef STAGE_ZNT
}

// ---------------------------------------------------------------------------
// K3: triangle einsum. Per channel h: X_h = A_h * B_h^T (bf16 NT).
// 128x128 tile, BK=64. Counted-vmcnt pipeline (measured neutral vs
// __syncthreads in R8; kept for contention robustness). No stores mid-loop
// -> counts exact: 8 (next stage in flight) / 0 (last).
// XCD-aware remap (T1): each XCD gets 16 whole channels x 9 tiles; A_h+B_h
// (590KB) fits its 4MB L2 so the 3x panel re-reads hit L2.
// ---------------------------------------------------------------------------
__global__ __launch_bounds__(256) void k_tri(const u16* __restrict__ a,
                                             const u16* __restrict__ b,
                                             u16* __restrict__ x) {
  int n = blockIdx.x;
  int w = (n & 7) * 144 + (n >> 3);   // 1152 = 8 XCDs * 144
  int h = w / 9;
  int tile = w % 9;
  int tm = tile / 3, tn = tile % 3;
  int i0 = tm * 128, j0 = tn * 128;
  const u16* ah = a + (size_t)h * MTOT;
  const u16* bh = b + (size_t)h * MTOT;

  __shared__ u16 At[2][128][64];
  __shared__ u16 Bt[2][128][64];

  int lane = threadIdx.x & 63;
  int wvu = __builtin_amdgcn_readfirstlane(threadIdx.x >> 6);
  int nl = lane & 31, s = lane >> 5;
  int wr = wvu >> 1, wc = wvu & 1;
  int rl = lane >> 3, p8 = lane & 7;

  f32x16 acc[4];
#pragma unroll
  for (int q = 0; q < 4; ++q)
#pragma unroll
    for (int i = 0; i < 16; ++i) acc[q][i] = 0;

#define STAGE_TRI(bf, k0)                                                     \
  {                                                                           \
    _Pragma("unroll")                                                         \
    for (int j = 0; j < 4; ++j) {                                             \
      int row = wvu * 32 + j * 8 + rl;                                        \
      int gc = (p8 ^ (rl & 7)) << 3;                                          \
      gl16(ah + (size_t)(i0 + row) * NRES + (k0) + gc, &At[bf][wvu * 32 + j * 8][0]); \
      gl16(bh + (size_t)(j0 + row) * NRES + (k0) + gc, &Bt[bf][wvu * 32 + j * 8][0]); \
    }                                                                         \
  }

  asm volatile("" ::: "memory");
  STAGE_TRI(0, 0);        // G0 -> b0
  asm volatile("" ::: "memory");
  STAGE_TRI(1, 64);       // G1 -> b1
  asm volatile("" ::: "memory");

#define TRI_ITER(kb, WAITINSN, STAGEIT)                                       \
  {                                                                           \
    const int cur = (kb) & 1;                                                 \
    asm volatile(WAITINSN ::: "memory");                                      \
    __builtin_amdgcn_s_barrier();                                             \
    asm volatile("" ::: "memory");                                            \
    _Pragma("unroll")                                                         \
    for (int kk = 0; kk < 4; ++kk) {                                          \
      int c = ((kk * 2 + s) ^ (nl & 7)) << 3;                                 \
      bf16x8 af0 = *(const bf16x8*)&At[cur][wr * 64 + nl][c];                 \
      bf16x8 af1 = *(const bf16x8*)&At[cur][wr * 64 + 32 + nl][c];            \
      bf16x8 bf0 = *(const bf16x8*)&Bt[cur][wc * 64 + nl][c];                 \
      bf16x8 bf1 = *(const bf16x8*)&Bt[cur][wc * 64 + 32 + nl][c];            \
      acc[0] = __builtin_amdgcn_mfma_f32_32x32x16_bf16(af0, bf0, acc[0], 0, 0, 0); \
      acc[1] = __builtin_amdgcn_mfma_f32_32x32x16_bf16(af0, bf1, acc[1], 0, 0, 0); \
      acc[2] = __builtin_amdgcn_mfma_f32_32x32x16_bf16(af1, bf0, acc[2], 0, 0, 0); \
      acc[3] = __builtin_amdgcn_mfma_f32_32x32x16_bf16(af1, bf1, acc[3], 0, 0, 0); \
    }                                                                         \
    asm volatile("s_waitcnt lgkmcnt(0)" ::: "memory");                        \
    if (STAGEIT) {                                                            \
      __builtin_amdgcn_s_barrier();   /* buffer reads done; drain-free */     \
      asm volatile("" ::: "memory");                                          \
      STAGE_TRI(cur, ((kb) + 2) * 64);                                        \
      asm volatile("" ::: "memory");                                          \
    }                                                                         \
  }

  TRI_ITER(0, "s_waitcnt vmcnt(8)", 1);   // awaits G0; G1 in flight; G2->b0
  TRI_ITER(1, "s_waitcnt vmcnt(8)", 1);   // awaits G1; G2 in flight; G3->b1
  TRI_ITER(2, "s_waitcnt vmcnt(8)", 1);   // awaits G2; G3 in flight; G4->b0
  TRI_ITER(3, "s_waitcnt vmcnt(8)", 1);   // awaits G3; G4 in flight; G5->b1
  TRI_ITER(4, "s_waitcnt vmcnt(8)", 0);   // awaits G4; G5 in flight
  TRI_ITER(5, "s_waitcnt vmcnt(0)", 0);   // awaits G5 (last)
#undef TRI_ITER
#undef STAGE_TRI

  u16* xh = x + (size_t)h * MTOT;
#pragma unroll
  for (int msub = 0; msub < 2; ++msub)
#pragma unroll
    for (int nsub = 0; nsub < 2; ++nsub) {
      int j = j0 + wc * 64 + nsub * 32 + nl;
#pragma unroll
      for (int r = 0; r < 16; ++r) {
        int i = i0 + wr * 64 + msub * 32 + (r & 3) + 8 * (r >> 2) + 4 * s;
        xh[(size_t)i * NRES + j] = f2bf(acc[msub * 2 + nsub][r]);
      }
    }
}

// ---------------------------------------------------------------------------
// K4: out[m][o] = sigmoid(zn.g_w^T + g_b)[m][o]
//               * ( rs[m]*(x.W'^T)[m][o] - rs[m]*mu[m]*c1[o] + c2[o] )
// LN folded algebraically (W' = ln_out_w (.) z_w, c1/c2 precomputed):
// no normalize write-back pass, GEMM runs on the RAW transposed x tile.
// Load-order discipline: zn loads -> gwf/gb -> x prefetch; lgkm-only raw
// barriers. vmcnt retires in order, so the zn/gwf waits never drain the
// younger x loads -> x HBM latency hides under the gate GEMM (T14).
// ---------------------------------------------------------------------------
__global__ __launch_bounds__(256) void k_out(
    const u16* __restrict__ x, const u16* __restrict__ zn,
    const u16* __restrict__ wb, const float* __restrict__ gb,
    const float2* __restrict__ c12, float* __restrict__ out) {
  int m0 = blockIdx.x * 64;
  int t = threadIdx.x;
  int wv = t >> 6, lane = t & 63, nl = lane & 31, s = lane >> 5;
  int o = wv * 32 + nl;

  __shared__ u16 tile[64][136];
  __shared__ float2 stat[64];   // {rs, rs*mu} per m-row

  const u16* gwp = wb + 4 * 16384;   // g_w
  const u16* zwp = wb + 5 * 16384;   // W' = z_w with ln_out_w folded

  // ---- issue order: zn(oldest) -> gwf,gb -> x(youngest)
  uint4 znv[4];
#pragma unroll
  for (int it = 0; it < 4; ++it) {
    int idx = it * 256 + t, r = idx >> 4, c8 = idx & 15;
    znv[it] = *(const uint4*)(zn + (size_t)(m0 + r) * CD + c8 * 8);
  }
  bf16x8 gwf[8];
#pragma unroll
  for (int kk = 0; kk < 8; ++kk)
    gwf[kk] = *(const bf16x8*)(gwp + o * CD + kk * 16 + s * 8);
  float gbv = gb[o];

  int mc = t & 7;
  uint4 xv0[2], xv1[2];
#pragma unroll
  for (int ps = 0; ps < 2; ++ps) {
    int hp = (ps * 256 + t) >> 3;
    xv0[ps] = *(const uint4*)(x + (size_t)(2 * hp)     * MTOT + m0 + mc * 8);
    xv1[ps] = *(const uint4*)(x + (size_t)(2 * hp + 1) * MTOT + m0 + mc * 8);
  }

  // stage zn -> tile (waits only zn; x stays in flight)
#pragma unroll
  for (int it = 0; it < 4; ++it) {
    int idx = it * 256 + t, r = idx >> 4, c8 = idx & 15;
    *(uint4*)&tile[r][c8 * 8] = znv[it];
  }
  asm volatile("s_waitcnt lgkmcnt(0)" ::: "memory");
  __builtin_amdgcn_s_barrier();

  // ---- phase A: gate GEMM (C[m][o])
  f32x16 gacc[2];
#pragma unroll
  for (int i = 0; i < 16; ++i) { gacc[0][i] = 0; gacc[1][i] = 0; }
#pragma unroll
  for (int kk = 0; kk < 8; ++kk) {
    bf16x8 zf0 = *(const bf16x8*)&tile[nl][kk * 16 + s * 8];
    bf16x8 zf1 = *(const bf16x8*)&tile[32 + nl][kk * 16 + s * 8];
    gacc[0] = __builtin_amdgcn_mfma_f32_32x32x16_bf16(zf0, gwf[kk], gacc[0], 0, 0, 0);
    gacc[1] = __builtin_amdgcn_mfma_f32_32x32x16_bf16(zf1, gwf[kk], gacc[1], 0, 0, 0);
  }
  float gv[32];
#pragma unroll
  for (int ms = 0; ms < 2; ++ms)
#pragma unroll
    for (int r = 0; r < 16; ++r)
      gv[ms * 16 + r] = sigmoidf(gacc[ms][r] + gbv);
  asm volatile("s_waitcnt lgkmcnt(0)" ::: "memory");
  __builtin_amdgcn_s_barrier();   // all waves done reading zn tile

  // W' fragments (younger than x; x-waits below don't drain these)
  bf16x8 zwf[8];
#pragma unroll
  for (int kk = 0; kk < 8; ++kk)
    zwf[kk] = *(const bf16x8*)(zwp + o * CD + kk * 16 + s * 8);

  // ---- phase B: transpose x[h][m] -> tile[m][h] (consumes prefetched regs)
#pragma unroll
  for (int ps = 0; ps < 2; ++ps) {
    int hp = (ps * 256 + t) >> 3;
    unsigned c0[4] = {xv0[ps].x, xv0[ps].y, xv0[ps].z, xv0[ps].w};
    unsigned c1[4] = {xv1[ps].x, xv1[ps].y, xv1[ps].z, xv1[ps].w};
#pragma unroll
    for (int q = 0; q < 4; ++q) {
      ushort2 lo, hi;
      lo.x = (u16)(c0[q] & 0xffffu); lo.y = (u16)(c1[q] & 0xffffu);
      hi.x = (u16)(c0[q] >> 16);     hi.y = (u16)(c1[q] >> 16);
      *(ushort2*)&tile[mc * 8 + 2 * q][2 * hp]     = lo;
      *(ushort2*)&tile[mc * 8 + 2 * q + 1][2 * hp] = hi;
    }
  }
  asm volatile("s_waitcnt lgkmcnt(0)" ::: "memory");
  __builtin_amdgcn_s_barrier();

  // ---- stats: one-pass mean/var per m-row (4x b128 reads, no write-back)
  {
    int r = t >> 2, q = t & 3;
    float sum = 0.0f, sq = 0.0f;
#pragma unroll
    for (int i = 0; i < 4; ++i) {
      uint4 v = *(const uint4*)&tile[r][q * 32 + i * 8];
      unsigned cc[4] = {v.x, v.y, v.z, v.w};
#pragma unroll
      for (int j = 0; j < 4; ++j) {
        float a = bf2f((u16)(cc[j] & 0xffffu));
        float b = bf2f((u16)(cc[j] >> 16));
        sum += a + b; sq += a * a + b * b;
      }
    }
    sum += __shfl_xor(sum, 1); sum += __shfl_xor(sum, 2);
    sq  += __shfl_xor(sq, 1);  sq  += __shfl_xor(sq, 2);
    float mu = sum * (1.0f / CD);
    float var = sq * (1.0f / CD) - mu * mu;
    float rs = rsqrtf(var + 1e-5f);
    if (q == 0) stat[r] = make_float2(rs, rs * mu);
  }

  // ---- W' GEMM on the raw x tile (reads only; no barrier needed vs stats)
  f32x16 acc[2];
#pragma unroll
  for (int i = 0; i < 16; ++i) { acc[0][i] = 0; acc[1][i] = 0; }
#pragma unroll
  for (int kk = 0; kk < 8; ++kk) {
    bf16x8 af0 = *(const bf16x8*)&tile[nl][kk * 16 + s * 8];
    bf16x8 af1 = *(const bf16x8*)&tile[32 + nl][kk * 16 + s * 8];
    acc[0] = __builtin_amdgcn_mfma_f32_32x32x16_bf16(af0, zwf[kk], acc[0], 0, 0, 0);
    acc[1] = __builtin_amdgcn_mfma_f32_32x32x16_bf16(af1, zwf[kk], acc[1], 0, 0, 0);
  }
  asm volatile("s_waitcnt lgkmcnt(0)" ::: "memory");
  __builtin_amdgcn_s_barrier();   // stat[] visible to all

  float2 cc2 = c12[o];
#pragma unroll
  for (int ms = 0; ms < 2; ++ms)
#pragma unroll
    for (int rr = 0; rr < 16; ++rr) {
      int rowoff = (rr & 3) + 8 * (rr >> 2) + 4 * s;
      int row = ms * 32 + rowoff;
      float2 st = stat[row];
      out[(size_t)(m0 + row) * CD + o] =
          gv[ms * 16 + rr] * (st.x * acc[ms][rr] - st.y * cc2.x + cc2.y);
    }
}

// ---------------------------------------------------------------------------
extern "C" void kernel_launch(void* const* d_in, const int* in_sizes, int n_in,
                              void* d_out, int out_size, void* d_ws, size_t ws_size,
                              hipStream_t stream) {
  const float* z       = (const float*)d_in[0];
  const float* mask    = (const float*)d_in[1];
  const float* ln_in_w = (const float*)d_in[2];
  const float* ln_in_b = (const float*)d_in[3];
  const float* a_g_w   = (const float*)d_in[4];
  const float* a_g_b   = (const float*)d_in[5];
  const float* a_p_w   = (const float*)d_in[6];
  const float* a_p_b   = (const float*)d_in[7];
  const float* b_g_w   = (const float*)d_in[8];
  const float* b_g_b   = (const float*)d_in[9];
  const float* b_p_w   = (const float*)d_in[10];
  const float* b_p_b   = (const float*)d_in[11];
  const float* g_w     = (const float*)d_in[12];
  const float* g_b     = (const float*)d_in[13];
  const float* ln_o_w  = (const float*)d_in[14];
  const float* ln_o_b  = (const float*)d_in[15];
  const float* z_w     = (const float*)d_in[16];
  const float* z_b     = (const float*)d_in[17];
  float* out = (float*)d_out;

  const size_t SZ = (size_t)MTOT * CD * sizeof(u16);
  char* w = (char*)d_ws;
  u16* zn = (u16*)(w);              // live until k_out
  u16* a  = (u16*)(w + SZ);
  u16* b  = (u16*)(w + 2 * SZ);
  u16* x  = (u16*)(w + 3 * SZ);
  u16* wb = (u16*)(w + 4 * SZ);
  float2* c12 = (float2*)(w + 4 * SZ + 6 * 16384 * sizeof(u16));
  (void)ws_size; (void)in_sizes; (void)n_in; (void)out_size;

  k_cvt_w<<<384, 256, 0, stream>>>(a_g_w, a_p_w, b_g_w, b_p_w, g_w, z_w,
                                   ln_o_w, wb);
  k_c12<<<128, 64, 0, stream>>>(z_w, ln_o_w, ln_o_b, z_b, c12);
  k_ln_in<<<MTOT / 32, 256, 0, stream>>>(z, ln_in_w, ln_in_b, zn);
  k_proj<<<dim3(MTOT / 256, 2), 256, 0, stream>>>(zn, mask, wb,
      a_g_b, a_p_b, b_g_b, b_p_b, a, b);
  k_tri<<<1152, 256, 0, stream>>>(a, b, x);
  k_out<<<MTOT / 64, 256, 0, stream>>>(x, zn, wb, g_b, c12, out);
}

// Round 10
// 269.082 us; speedup vs baseline: 1.0202x; 1.0039x over previous
//
#include <hip/hip_runtime.h>

#define NRES 384
#define CD   128
#define MTOT (NRES*NRES)   /* 147456 */

typedef unsigned short u16;
typedef __bf16 bf16x8 __attribute__((ext_vector_type(8)));
typedef float  f32x16 __attribute__((ext_vector_type(16)));

static __device__ __forceinline__ u16 f2bf(float f) {
  __bf16 b = (__bf16)f;
  return __builtin_bit_cast(u16, b);
}
static __device__ __forceinline__ float bf2f(u16 v) {
  return __uint_as_float(((unsigned)v) << 16);
}
static __device__ __forceinline__ float sigmoidf(float x) {
  // v_exp + v_add + v_rcp: avoids the precise-IEEE div sequence (no fast-math flags)
  return __builtin_amdgcn_rcpf(1.0f + __expf(-x));
}

// async global->LDS, 16B per lane; LDS dest = wave-uniform base + lane*16
static __device__ __forceinline__ void gl16(const void* g, void* l) {
  __builtin_amdgcn_global_load_lds(
      (const __attribute__((address_space(1))) void*)g,
      (__attribute__((address_space(3))) void*)l, 16, 0, 0);
}

// ---------------------------------------------------------------------------
// K0: convert the six 128x128 fp32 weight matrices to bf16 (row-major [n][k])
// order in wb: a_g_w, a_p_w, b_g_w, b_p_w, g_w, z_w' (z_w with ln_out_w folded)
// which-matrix select is BLOCK-uniform (64 blocks per matrix) -> SGPR select.
// ---------------------------------------------------------------------------
__global__ void k_cvt_w(const float* w0, const float* w1, const float* w2,
                        const float* w3, const float* w4, const float* w5,
                        const float* lnw, u16* wb) {
  int i = blockIdx.x * 256 + threadIdx.x;
  int which = blockIdx.x >> 6;   // uniform per block
  const float* src = (which == 0) ? w0 : (which == 1) ? w1 : (which == 2) ? w2
                   : (which == 3) ? w3 : (which == 4) ? w4 : w5;
  float v = src[i & 16383];
  if (which == 5) v *= lnw[i & 127];   // fold ln_out_w into z_w
  wb[i] = f2bf(v);
}

// ---------------------------------------------------------------------------
// K0b: c1[o] = sum_h ln_out_w[h]*z_w[o][h]; c2[o] = sum_h ln_out_b[h]*z_w[o][h] + z_b[o]
// These make LN(x).z_w^T = rs*(x.W'^T) - rs*mu*c1 + c2  (W' = ln_out_w (.) z_w)
// ---------------------------------------------------------------------------
__global__ void k_c12(const float* __restrict__ zw, const float* __restrict__ lnw,
                      const float* __restrict__ lnb, const float* __restrict__ zb,
                      float2* __restrict__ c12) {
  int o = blockIdx.x, l = threadIdx.x;
  float2 v = ((const float2*)(zw + o * CD))[l];
  float2 w = ((const float2*)lnw)[l];
  float2 b = ((const float2*)lnb)[l];
  float s1 = v.x * w.x + v.y * w.y;
  float s2 = v.x * b.x + v.y * b.y;
#pragma unroll
  for (int off = 32; off >= 1; off >>= 1) {
    s1 += __shfl_xor(s1, off);
    s2 += __shfl_xor(s2, off);
  }
  if (l == 0) c12[o] = make_float2(s1, s2 + zb[o]);
}

// ---------------------------------------------------------------------------
// K1: LayerNorm(z) -> zn bf16 [m][c]. REVERTED to R6-proven form: the R8/R9
// float4/32-lane-group rewrite regressed ~+9.5us (cross-round arithmetic
// with k_proj@47.16 as the machine anchor).
// ---------------------------------------------------------------------------
__global__ __launch_bounds__(256) void k_ln_in(const float* __restrict__ z,
                                               const float* __restrict__ w,
                                               const float* __restrict__ b,
                                               u16* __restrict__ zn) {
  int wv = threadIdx.x >> 6, lane = threadIdx.x & 63;
  float2 wv2 = ((const float2*)w)[lane];
  float2 bv2 = ((const float2*)b)[lane];
  for (int rr = 0; rr < 4; ++rr) {
    size_t row = (size_t)blockIdx.x * 16 + wv * 4 + rr;
    float2 v = ((const float2*)(z + row * CD))[lane];
    float s = v.x + v.y;
#pragma unroll
    for (int off = 32; off >= 1; off >>= 1) s += __shfl_xor(s, off);
    float mu = s * (1.0f / CD);
    float dx = v.x - mu, dy = v.y - mu;
    float vr = dx * dx + dy * dy;
#pragma unroll
    for (int off = 32; off >= 1; off >>= 1) vr += __shfl_xor(vr, off);
    float rs = rsqrtf(vr * (1.0f / CD) + 1e-5f);
    ushort2 o;
    o.x = f2bf(dx * rs * wv2.x + bv2.x);
    o.y = f2bf(dy * rs * wv2.y + bv2.y);
    ((ushort2*)(zn + row * CD))[lane] = o;
  }
}

// ---------------------------------------------------------------------------
// K2: a/b projections off zn. 128-ROW TILES (was 256): 2x64-row subtiles,
// BOTH prologue-staged into 2 LDS buffers -> zero mid-loop staging, 2
// barriers/block (was 4), LDS 33KB -> 4 blocks/CU (was 3@50KB), grid 2304
// (was 1152) for TLP + tail. The iteration macro is byte-identical to the
// R6 HW-proven form (no new live ranges -> VGPR stays ~104; R8's failure
// mode was restructured staging raising VGPR to 136).
// EXACT counted vmcnt (retires in issue order; fences pin positions):
//   iter0 awaits G0: younger = G1(4)        -> vmcnt(4)
//   iter1 awaits G1: younger = stores0(32)  -> vmcnt(32)
// Flattened grid + pair-preserving XCD remap: w=(n&7)*288+(n>>3) (bijective,
// 2304%8==0); pair=w>>1, type=w&1 -> both types of one zn tile land on the
// same XCD adjacent in time -> type-1's zn read is an L2 hit.
// LDS 16-slot XOR swizzle (bank-conflict-free, verified 1.18M -> 0 in R6).
// ---------------------------------------------------------------------------
__global__ __launch_bounds__(256) void k_proj(
    const u16* __restrict__ zn, const float* __restrict__ mask,
    const u16* __restrict__ wb,
    const float* __restrict__ agb, const float* __restrict__ apb,
    const float* __restrict__ bgb, const float* __restrict__ bpb,
    u16* __restrict__ a_out, u16* __restrict__ b_out) {
  int n = blockIdx.x;
  int w = (n & 7) * 288 + (n >> 3);   // 2304 = 8 XCDs * 288
  int type = w & 1;
  int m_base = (w >> 1) * 128;
  int t = threadIdx.x;
  int lane = t & 63;
  int wvu = __builtin_amdgcn_readfirstlane(t >> 6);
  int nl = lane & 31, s = lane >> 5;
  int h = wvu * 32 + nl;

  const u16* wgp = wb + (size_t)type * 32768;
  const u16* wpp = wgp + 16384;
  const float* bgp = (type == 0) ? agb : bgb;
  const float* bpp = (type == 0) ? apb : bpb;
  u16* outp = (type == 0) ? a_out : b_out;

  __shared__ u16 znt[2][64][128];   // 32 KB, 16-slot swizzled
  __shared__ float bsl[2][128];     // biases (gate, proj)

  if (t < 128) bsl[0][t] = bgp[t];
  else         bsl[1][t - 128] = bpp[t - 128];

  float mk0[2], mk1[2];
#pragma unroll
  for (int ms = 0; ms < 2; ++ms) {
    mk0[ms] = mask[m_base + ms * 64 + nl];
    mk1[ms] = mask[m_base + ms * 64 + 32 + nl];
  }

  bf16x8 wgf[8], wpf[8];
#pragma unroll
  for (int kk = 0; kk < 8; ++kk) {
    wgf[kk] = *(const bf16x8*)(wgp + h * CD + kk * 16 + s * 8);
    wpf[kk] = *(const bf16x8*)(wpp + h * CD + kk * 16 + s * 8);
  }

  int rl = lane >> 4, p16 = lane & 15;
#define STAGE_ZNT(mt, bf)                                                   \
  {                                                                         \
    _Pragma("unroll")                                                       \
    for (int j = 0; j < 4; ++j) {                                           \
      int row = wvu * 16 + j * 4 + rl;                                      \
      int gc = (p16 ^ (row & 15)) << 3;                                     \
      gl16(zn + (size_t)((mt) + row) * CD + gc, &znt[bf][wvu * 16 + j * 4][0]); \
    }                                                                       \
  }

  asm volatile("" ::: "memory");
  STAGE_ZNT(m_base, 0);          // G0
  asm volatile("" ::: "memory");
  STAGE_ZNT(m_base + 64, 1);     // G1
  asm volatile("" ::: "memory");

  asm volatile("s_waitcnt lgkmcnt(0)" ::: "memory");  // bias ds_writes done

#define PROJ_ITER(ms, buf, WAITINSN)                                          \
  {                                                                           \
    asm volatile(WAITINSN ::: "memory");                                      \
    __builtin_amdgcn_s_barrier();                                             \
    asm volatile("" ::: "memory");                                            \
    f32x16 accg0, accg1, accp0, accp1;                                        \
    _Pragma("unroll")                                                         \
    for (int i = 0; i < 16; ++i) {                                            \
      accg0[i] = 0; accg1[i] = 0; accp0[i] = 0; accp1[i] = 0;                 \
    }                                                                         \
    _Pragma("unroll")                                                         \
    for (int kk = 0; kk < 8; ++kk) {                                          \
      int c = ((kk * 2 + s) ^ (nl & 15)) << 3;                                \
      bf16x8 zf0 = *(const bf16x8*)&znt[buf][nl][c];                          \
      bf16x8 zf1 = *(const bf16x8*)&znt[buf][32 + nl][c];                     \
      accg0 = __builtin_amdgcn_mfma_f32_32x32x16_bf16(wgf[kk], zf0, accg0, 0, 0, 0); \
      accg1 = __builtin_amdgcn_mfma_f32_32x32x16_bf16(wgf[kk], zf1, accg1, 0, 0, 0); \
      accp0 = __builtin_amdgcn_mfma_f32_32x32x16_bf16(wpf[kk], zf0, accp0, 0, 0, 0); \
      accp1 = __builtin_amdgcn_mfma_f32_32x32x16_bf16(wpf[kk], zf1, accp1, 0, 0, 0); \
    }                                                                         \
    int mt = m_base + (ms) * 64;                                              \
    _Pragma("unroll")                                                         \
    for (int r = 0; r < 16; ++r) {                                            \
      int hh = wvu * 32 + (r & 3) + 8 * (r >> 2) + 4 * s;                     \
      float bg = bsl[0][hh], bp = bsl[1][hh];                                 \
      u16* rowp = outp + (size_t)hh * MTOT + mt + nl;                         \
      rowp[0]  = f2bf(mk0[ms] * sigmoidf(accg0[r] + bg) * (accp0[r] + bp));   \
      rowp[32] = f2bf(mk1[ms] * sigmoidf(accg1[r] + bg) * (accp1[r] + bp));   \
    }                                                                         \
    asm volatile("" ::: "memory");                                            \
  }

  PROJ_ITER(0, 0, "s_waitcnt vmcnt(4)");    // awaits G0; G1 in flight
  PROJ_ITER(1, 1, "s_waitcnt vmcnt(32)");   // awaits G1; stores0 in flight
#undef PROJ_ITER
#undef STAGE_ZNT
}

// ---------------------------------------------------------------------------
// K3: triangle einsum. Per channel h: X_h = A_h * B_h^T (bf16 NT).
// 128x128 tile, BK=64. Counted-vmcnt pipeline (measured neutral vs
// __syncthreads in R8; kept). No stores mid-loop -> counts exact: 8/0.
// XCD-aware remap (T1): each XCD gets 16 whole channels x 9 tiles; A_h+B_h
// (590KB) fits its 4MB L2 so the 3x panel re-reads hit L2.
// ---------------------------------------------------------------------------
__global__ __launch_bounds__(256) void k_tri(const u16* __restrict__ a,
                                             const u16* __restrict__ b,
                                             u16* __restrict__ x) {
  int n = blockIdx.x;
  int w = (n & 7) * 144 + (n >> 3);   // 1152 = 8 XCDs * 144
  int h = w / 9;
  int tile = w % 9;
  int tm = tile / 3, tn = tile % 3;
  int i0 = tm * 128, j0 = tn * 128;
  const u16* ah = a + (size_t)h * MTOT;
  const u16* bh = b + (size_t)h * MTOT;

  __shared__ u16 At[2][128][64];
  __shared__ u16 Bt[2][128][64];

  int lane = threadIdx.x & 63;
  int wvu = __builtin_amdgcn_readfirstlane(threadIdx.x >> 6);
  int nl = lane & 31, s = lane >> 5;
  int wr = wvu >> 1, wc = wvu & 1;
  int rl = lane >> 3, p8 = lane & 7;

  f32x16 acc[4];
#pragma unroll
  for (int q = 0; q < 4; ++q)
#pragma unroll
    for (int i = 0; i < 16; ++i) acc[q][i] = 0;

#define STAGE_TRI(bf, k0)                                                     \
  {                                                                           \
    _Pragma("unroll")                                                         \
    for (int j = 0; j < 4; ++j) {                                             \
      int row = wvu * 32 + j * 8 + rl;                                        \
      int gc = (p8 ^ (rl & 7)) << 3;                                          \
      gl16(ah + (size_t)(i0 + row) * NRES + (k0) + gc, &At[bf][wvu * 32 + j * 8][0]); \
      gl16(bh + (size_t)(j0 + row) * NRES + (k0) + gc, &Bt[bf][wvu * 32 + j * 8][0]); \
    }                                                                         \
  }

  asm volatile("" ::: "memory");
  STAGE_TRI(0, 0);        // G0 -> b0
  asm volatile("" ::: "memory");
  STAGE_TRI(1, 64);       // G1 -> b1
  asm volatile("" ::: "memory");

#define TRI_ITER(kb, WAITINSN, STAGEIT)                                       \
  {                                                                           \
    const int cur = (kb) & 1;                                                 \
    asm volatile(WAITINSN ::: "memory");                                      \
    __builtin_amdgcn_s_barrier();                                             \
    asm volatile("" ::: "memory");                                            \
    _Pragma("unroll")                                                         \
    for (int kk = 0; kk < 4; ++kk) {                                          \
      int c = ((kk * 2 + s) ^ (nl & 7)) << 3;                                 \
      bf16x8 af0 = *(const bf16x8*)&At[cur][wr * 64 + nl][c];                 \
      bf16x8 af1 = *(const bf16x8*)&At[cur][wr * 64 + 32 + nl][c];            \
      bf16x8 bf0 = *(const bf16x8*)&Bt[cur][wc * 64 + nl][c];                 \
      bf16x8 bf1 = *(const bf16x8*)&Bt[cur][wc * 64 + 32 + nl][c];            \
      acc[0] = __builtin_amdgcn_mfma_f32_32x32x16_bf16(af0, bf0, acc[0], 0, 0, 0); \
      acc[1] = __builtin_amdgcn_mfma_f32_32x32x16_bf16(af0, bf1, acc[1], 0, 0, 0); \
      acc[2] = __builtin_amdgcn_mfma_f32_32x32x16_bf16(af1, bf0, acc[2], 0, 0, 0); \
      acc[3] = __builtin_amdgcn_mfma_f32_32x32x16_bf16(af1, bf1, acc[3], 0, 0, 0); \
    }                                                                         \
    asm volatile("s_waitcnt lgkmcnt(0)" ::: "memory");                        \
    if (STAGEIT) {                                                            \
      __builtin_amdgcn_s_barrier();   /* buffer reads done; drain-free */     \
      asm volatile("" ::: "memory");                                          \
      STAGE_TRI(cur, ((kb) + 2) * 64);                                        \
      asm volatile("" ::: "memory");                                          \
    }                                                                         \
  }

  TRI_ITER(0, "s_waitcnt vmcnt(8)", 1);   // awaits G0; G1 in flight; G2->b0
  TRI_ITER(1, "s_waitcnt vmcnt(8)", 1);   // awaits G1; G2 in flight; G3->b1
  TRI_ITER(2, "s_waitcnt vmcnt(8)", 1);   // awaits G2; G3 in flight; G4->b0
  TRI_ITER(3, "s_waitcnt vmcnt(8)", 1);   // awaits G3; G4 in flight; G5->b1
  TRI_ITER(4, "s_waitcnt vmcnt(8)", 0);   // awaits G4; G5 in flight
  TRI_ITER(5, "s_waitcnt vmcnt(0)", 0);   // awaits G5 (last)
#undef TRI_ITER
#undef STAGE_TRI

  u16* xh = x + (size_t)h * MTOT;
#pragma unroll
  for (int msub = 0; msub < 2; ++msub)
#pragma unroll
    for (int nsub = 0; nsub < 2; ++nsub) {
      int j = j0 + wc * 64 + nsub * 32 + nl;
#pragma unroll
      for (int r = 0; r < 16; ++r) {
        int i = i0 + wr * 64 + msub * 32 + (r & 3) + 8 * (r >> 2) + 4 * s;
        xh[(size_t)i * NRES + j] = f2bf(acc[msub * 2 + nsub][r]);
      }
    }
}

// ---------------------------------------------------------------------------
// K4: out[m][o] = sigmoid(zn.g_w^T + g_b)[m][o]
//               * ( rs[m]*(x.W'^T)[m][o] - rs[m]*mu[m]*c1[o] + c2[o] )
// LN folded algebraically (W' = ln_out_w (.) z_w, c1/c2 precomputed):
// no normalize write-back pass, GEMM runs on the RAW transposed x tile.
// Load-order discipline: zn loads -> gwf/gb -> x prefetch; lgkm-only raw
// barriers. vmcnt retires in order, so the zn/gwf waits never drain the
// younger x loads -> x HBM latency hides under the gate GEMM (T14).
// ---------------------------------------------------------------------------
__global__ __launch_bounds__(256) void k_out(
    const u16* __restrict__ x, const u16* __restrict__ zn,
    const u16* __restrict__ wb, const float* __restrict__ gb,
    const float2* __restrict__ c12, float* __restrict__ out) {
  int m0 = blockIdx.x * 64;
  int t = threadIdx.x;
  int wv = t >> 6, lane = t & 63, nl = lane & 31, s = lane >> 5;
  int o = wv * 32 + nl;

  __shared__ u16 tile[64][136];
  __shared__ float2 stat[64];   // {rs, rs*mu} per m-row

  const u16* gwp = wb + 4 * 16384;   // g_w
  const u16* zwp = wb + 5 * 16384;   // W' = z_w with ln_out_w folded

  // ---- issue order: zn(oldest) -> gwf,gb -> x(youngest)
  uint4 znv[4];
#pragma unroll
  for (int it = 0; it < 4; ++it) {
    int idx = it * 256 + t, r = idx >> 4, c8 = idx & 15;
    znv[it] = *(const uint4*)(zn + (size_t)(m0 + r) * CD + c8 * 8);
  }
  bf16x8 gwf[8];
#pragma unroll
  for (int kk = 0; kk < 8; ++kk)
    gwf[kk] = *(const bf16x8*)(gwp + o * CD + kk * 16 + s * 8);
  float gbv = gb[o];

  int mc = t & 7;
  uint4 xv0[2], xv1[2];
#pragma unroll
  for (int ps = 0; ps < 2; ++ps) {
    int hp = (ps * 256 + t) >> 3;
    xv0[ps] = *(const uint4*)(x + (size_t)(2 * hp)     * MTOT + m0 + mc * 8);
    xv1[ps] = *(const uint4*)(x + (size_t)(2 * hp + 1) * MTOT + m0 + mc * 8);
  }

  // stage zn -> tile (waits only zn; x stays in flight)
#pragma unroll
  for (int it = 0; it < 4; ++it) {
    int idx = it * 256 + t, r = idx >> 4, c8 = idx & 15;
    *(uint4*)&tile[r][c8 * 8] = znv[it];
  }
  asm volatile("s_waitcnt lgkmcnt(0)" ::: "memory");
  __builtin_amdgcn_s_barrier();

  // ---- phase A: gate GEMM (C[m][o])
  f32x16 gacc[2];
#pragma unroll
  for (int i = 0; i < 16; ++i) { gacc[0][i] = 0; gacc[1][i] = 0; }
#pragma unroll
  for (int kk = 0; kk < 8; ++kk) {
    bf16x8 zf0 = *(const bf16x8*)&tile[nl][kk * 16 + s * 8];
    bf16x8 zf1 = *(const bf16x8*)&tile[32 + nl][kk * 16 + s * 8];
    gacc[0] = __builtin_amdgcn_mfma_f32_32x32x16_bf16(zf0, gwf[kk], gacc[0], 0, 0, 0);
    gacc[1] = __builtin_amdgcn_mfma_f32_32x32x16_bf16(zf1, gwf[kk], gacc[1], 0, 0, 0);
  }
  float gv[32];
#pragma unroll
  for (int ms = 0; ms < 2; ++ms)
#pragma unroll
    for (int r = 0; r < 16; ++r)
      gv[ms * 16 + r] = sigmoidf(gacc[ms][r] + gbv);
  asm volatile("s_waitcnt lgkmcnt(0)" ::: "memory");
  __builtin_amdgcn_s_barrier();   // all waves done reading zn tile

  // W' fragments (younger than x; x-waits below don't drain these)
  bf16x8 zwf[8];
#pragma unroll
  for (int kk = 0; kk < 8; ++kk)
    zwf[kk] = *(const bf16x8*)(zwp + o * CD + kk * 16 + s * 8);

  // ---- phase B: transpose x[h][m] -> tile[m][h] (consumes prefetched regs)
#pragma unroll
  for (int ps = 0; ps < 2; ++ps) {
    int hp = (ps * 256 + t) >> 3;
    unsigned c0[4] = {xv0[ps].x, xv0[ps].y, xv0[ps].z, xv0[ps].w};
    unsigned c1[4] = {xv1[ps].x, xv1[ps].y, xv1[ps].z, xv1[ps].w};
#pragma unroll
    for (int q = 0; q < 4; ++q) {
      ushort2 lo, hi;
      lo.x = (u16)(c0[q] & 0xffffu); lo.y = (u16)(c1[q] & 0xffffu);
      hi.x = (u16)(c0[q] >> 16);     hi.y = (u16)(c1[q] >> 16);
      *(ushort2*)&tile[mc * 8 + 2 * q][2 * hp]     = lo;
      *(ushort2*)&tile[mc * 8 + 2 * q + 1][2 * hp] = hi;
    }
  }
  asm volatile("s_waitcnt lgkmcnt(0)" ::: "memory");
  __builtin_amdgcn_s_barrier();

  // ---- stats: one-pass mean/var per m-row (4x b128 reads, no write-back)
  {
    int r = t >> 2, q = t & 3;
    float sum = 0.0f, sq = 0.0f;
#pragma unroll
    for (int i = 0; i < 4; ++i) {
      uint4 v = *(const uint4*)&tile[r][q * 32 + i * 8];
      unsigned cc[4] = {v.x, v.y, v.z, v.w};
#pragma unroll
      for (int j = 0; j < 4; ++j) {
        float a = bf2f((u16)(cc[j] & 0xffffu));
        float b = bf2f((u16)(cc[j] >> 16));
        sum += a + b; sq += a * a + b * b;
      }
    }
    sum += __shfl_xor(sum, 1); sum += __shfl_xor(sum, 2);
    sq  += __shfl_xor(sq, 1);  sq  += __shfl_xor(sq, 2);
    float mu = sum * (1.0f / CD);
    float var = sq * (1.0f / CD) - mu * mu;
    float rs = rsqrtf(var + 1e-5f);
    if (q == 0) stat[r] = make_float2(rs, rs * mu);
  }

  // ---- W' GEMM on the raw x tile (reads only; no barrier needed vs stats)
  f32x16 acc[2];
#pragma unroll
  for (int i = 0; i < 16; ++i) { acc[0][i] = 0; acc[1][i] = 0; }
#pragma unroll
  for (int kk = 0; kk < 8; ++kk) {
    bf16x8 af0 = *(const bf16x8*)&tile[nl][kk * 16 + s * 8];
    bf16x8 af1 = *(const bf16x8*)&tile[32 + nl][kk * 16 + s * 8];
    acc[0] = __builtin_amdgcn_mfma_f32_32x32x16_bf16(af0, zwf[kk], acc[0], 0, 0, 0);
    acc[1] = __builtin_amdgcn_mfma_f32_32x32x16_bf16(af1, zwf[kk], acc[1], 0, 0, 0);
  }
  asm volatile("s_waitcnt lgkmcnt(0)" ::: "memory");
  __builtin_amdgcn_s_barrier();   // stat[] visible to all

  float2 cc2 = c12[o];
#pragma unroll
  for (int ms = 0; ms < 2; ++ms)
#pragma unroll
    for (int rr = 0; rr < 16; ++rr) {
      int rowoff = (rr & 3) + 8 * (rr >> 2) + 4 * s;
      int row = ms * 32 + rowoff;
      float2 st = stat[row];
      out[(size_t)(m0 + row) * CD + o] =
          gv[ms * 16 + rr] * (st.x * acc[ms][rr] - st.y * cc2.x + cc2.y);
    }
}

// ---------------------------------------------------------------------------
extern "C" void kernel_launch(void* const* d_in, const int* in_sizes, int n_in,
                              void* d_out, int out_size, void* d_ws, size_t ws_size,
                              hipStream_t stream) {
  const float* z       = (const float*)d_in[0];
  const float* mask    = (const float*)d_in[1];
  const float* ln_in_w = (const float*)d_in[2];
  const float* ln_in_b = (const float*)d_in[3];
  const float* a_g_w   = (const float*)d_in[4];
  const float* a_g_b   = (const float*)d_in[5];
  const float* a_p_w   = (const float*)d_in[6];
  const float* a_p_b   = (const float*)d_in[7];
  const float* b_g_w   = (const float*)d_in[8];
  const float* b_g_b   = (const float*)d_in[9];
  const float* b_p_w   = (const float*)d_in[10];
  const float* b_p_b   = (const float*)d_in[11];
  const float* g_w     = (const float*)d_in[12];
  const float* g_b     = (const float*)d_in[13];
  const float* ln_o_w  = (const float*)d_in[14];
  const float* ln_o_b  = (const float*)d_in[15];
  const float* z_w     = (const float*)d_in[16];
  const float* z_b     = (const float*)d_in[17];
  float* out = (float*)d_out;

  const size_t SZ = (size_t)MTOT * CD * sizeof(u16);
  char* w = (char*)d_ws;
  u16* zn = (u16*)(w);              // live until k_out
  u16* a  = (u16*)(w + SZ);
  u16* b  = (u16*)(w + 2 * SZ);
  u16* x  = (u16*)(w + 3 * SZ);
  u16* wb = (u16*)(w + 4 * SZ);
  float2* c12 = (float2*)(w + 4 * SZ + 6 * 16384 * sizeof(u16));
  (void)ws_size; (void)in_sizes; (void)n_in; (void)out_size;

  k_cvt_w<<<384, 256, 0, stream>>>(a_g_w, a_p_w, b_g_w, b_p_w, g_w, z_w,
                                   ln_o_w, wb);
  k_c12<<<128, 64, 0, stream>>>(z_w, ln_o_w, ln_o_b, z_b, c12);
  k_ln_in<<<MTOT / 16, 256, 0, stream>>>(z, ln_in_w, ln_in_b, zn);
  k_proj<<<2304, 256, 0, stream>>>(zn, mask, wb,
      a_g_b, a_p_b, b_g_b, b_p_b, a, b);
  k_tri<<<1152, 256, 0, stream>>>(a, b, x);
  k_out<<<MTOT / 64, 256, 0, stream>>>(x, zn, wb, g_b, c12, out);
}

// Round 11
// 257.569 us; speedup vs baseline: 1.0658x; 1.0447x over previous
//
#include <hip/hip_runtime.h>

#define NRES 384
#define CD   128
#define MTOT (NRES*NRES)   /* 147456 */

typedef unsigned short u16;
typedef __bf16 bf16x8 __attribute__((ext_vector_type(8)));
typedef float  f32x16 __attribute__((ext_vector_type(16)));

static __device__ __forceinline__ u16 f2bf(float f) {
  __bf16 b = (__bf16)f;
  return __builtin_bit_cast(u16, b);
}
static __device__ __forceinline__ float bf2f(u16 v) {
  return __uint_as_float(((unsigned)v) << 16);
}
static __device__ __forceinline__ float sigmoidf(float x) {
  // v_exp + v_add + v_rcp: avoids the precise-IEEE div sequence (no fast-math flags)
  return __builtin_amdgcn_rcpf(1.0f + __expf(-x));
}

// async global->LDS, 16B per lane; LDS dest = wave-uniform base + lane*16
static __device__ __forceinline__ void gl16(const void* g, void* l) {
  __builtin_amdgcn_global_load_lds(
      (const __attribute__((address_space(1))) void*)g,
      (__attribute__((address_space(3))) void*)l, 16, 0, 0);
}

// ---------------------------------------------------------------------------
// K_PREP: fused prep launch (was 3 kernels; all three parts are mutually
// independent, so block-range dispatch removes 2 stream-serialized launch
// gaps). Branches are block-uniform.
//   blocks [0, 9216):    LayerNorm(z) -> zn bf16 [m][c]  (R6-proven body)
//   blocks [9216, 9600): fp32->bf16 weight convert (wb; ln_out_w folded
//                        into z_w -> W')
//   blocks [9600, 9632): c12: c1[o]=sum ln_out_w*z_w[o][:];
//                        c2[o]=sum ln_out_b*z_w[o][:]+z_b[o]; 4 o per block.
// ---------------------------------------------------------------------------
#define PREP_LN_BLOCKS   (MTOT / 16)          /* 9216 */
#define PREP_W_BLOCKS    384
#define PREP_C12_BLOCKS  32
#define PREP_BLOCKS      (PREP_LN_BLOCKS + PREP_W_BLOCKS + PREP_C12_BLOCKS)

__global__ __launch_bounds__(256) void k_prep(
    const float* __restrict__ z, const float* __restrict__ lnw_in,
    const float* __restrict__ lnb_in, u16* __restrict__ zn,
    const float* w0, const float* w1, const float* w2,
    const float* w3, const float* w4, const float* w5,
    const float* __restrict__ lnw_out, const float* __restrict__ lnb_out,
    const float* __restrict__ zb, u16* __restrict__ wb,
    float2* __restrict__ c12) {
  int bid = blockIdx.x;
  int t = threadIdx.x;

  if (bid < PREP_LN_BLOCKS) {
    // ---- LayerNorm(z) -> zn (R6-proven form)
    int wv = t >> 6, lane = t & 63;
    float2 wv2 = ((const float2*)lnw_in)[lane];
    float2 bv2 = ((const float2*)lnb_in)[lane];
    for (int rr = 0; rr < 4; ++rr) {
      size_t row = (size_t)bid * 16 + wv * 4 + rr;
      float2 v = ((const float2*)(z + row * CD))[lane];
      float s = v.x + v.y;
#pragma unroll
      for (int off = 32; off >= 1; off >>= 1) s += __shfl_xor(s, off);
      float mu = s * (1.0f / CD);
      float dx = v.x - mu, dy = v.y - mu;
      float vr = dx * dx + dy * dy;
#pragma unroll
      for (int off = 32; off >= 1; off >>= 1) vr += __shfl_xor(vr, off);
      float rs = rsqrtf(vr * (1.0f / CD) + 1e-5f);
      ushort2 o;
      o.x = f2bf(dx * rs * wv2.x + bv2.x);
      o.y = f2bf(dy * rs * wv2.y + bv2.y);
      ((ushort2*)(zn + row * CD))[lane] = o;
    }
  } else if (bid < PREP_LN_BLOCKS + PREP_W_BLOCKS) {
    // ---- weight convert (which is block-uniform -> SGPR select)
    int rb = bid - PREP_LN_BLOCKS;
    int i = rb * 256 + t;
    int which = rb >> 6;
    const float* src = (which == 0) ? w0 : (which == 1) ? w1 : (which == 2) ? w2
                     : (which == 3) ? w3 : (which == 4) ? w4 : w5;
    float v = src[i & 16383];
    if (which == 5) v *= lnw_out[i & 127];   // fold ln_out_w into z_w
    wb[i] = f2bf(v);
  } else {
    // ---- c12: 4 outputs per block, one 64-lane wave each
    int o = (bid - PREP_LN_BLOCKS - PREP_W_BLOCKS) * 4 + (t >> 6);
    int l = t & 63;
    float2 v = ((const float2*)(w5 + o * CD))[l];   // w5 = z_w (raw fp32)
    float2 w = ((const float2*)lnw_out)[l];
    float2 b = ((const float2*)lnb_out)[l];
    float s1 = v.x * w.x + v.y * w.y;
    float s2 = v.x * b.x + v.y * b.y;
#pragma unroll
    for (int off = 32; off >= 1; off >>= 1) {
      s1 += __shfl_xor(s1, off);
      s2 += __shfl_xor(s2, off);
    }
    if (l == 0) c12[o] = make_float2(s1, s2 + zb[o]);
  }
}

// ---------------------------------------------------------------------------
// K2: a/b projections off zn. 128-row tiles: 2x64-row subtiles, both
// prologue-staged into 2 LDS buffers (33KB), zero mid-loop staging, 2
// barriers/block. EXACT counted vmcnt (proven R5/R6/R10):
//   iter0 awaits G0: younger = G1(4)        -> vmcnt(4)
//   iter1 awaits G1: younger = stores0(32)  -> vmcnt(32)
// Flattened grid + pair-preserving XCD remap (w=(n&7)*288+(n>>3), bijective):
// both type-blocks of one zn tile land on the same XCD adjacent in time ->
// FETCH halved (38.5 -> 19.3 MB, verified R10).
// LDS 16-slot XOR swizzle (bank-conflict-free, verified R6).
// ---------------------------------------------------------------------------
__global__ __launch_bounds__(256) void k_proj(
    const u16* __restrict__ zn, const float* __restrict__ mask,
    const u16* __restrict__ wb,
    const float* __restrict__ agb, const float* __restrict__ apb,
    const float* __restrict__ bgb, const float* __restrict__ bpb,
    u16* __restrict__ a_out, u16* __restrict__ b_out) {
  int n = blockIdx.x;
  int w = (n & 7) * 288 + (n >> 3);   // 2304 = 8 XCDs * 288
  int type = w & 1;
  int m_base = (w >> 1) * 128;
  int t = threadIdx.x;
  int lane = t & 63;
  int wvu = __builtin_amdgcn_readfirstlane(t >> 6);
  int nl = lane & 31, s = lane >> 5;
  int h = wvu * 32 + nl;

  const u16* wgp = wb + (size_t)type * 32768;
  const u16* wpp = wgp + 16384;
  const float* bgp = (type == 0) ? agb : bgb;
  const float* bpp = (type == 0) ? apb : bpb;
  u16* outp = (type == 0) ? a_out : b_out;

  __shared__ u16 znt[2][64][128];   // 32 KB, 16-slot swizzled
  __shared__ float bsl[2][128];     // biases (gate, proj)

  if (t < 128) bsl[0][t] = bgp[t];
  else         bsl[1][t - 128] = bpp[t - 128];

  float mk0[2], mk1[2];
#pragma unroll
  for (int ms = 0; ms < 2; ++ms) {
    mk0[ms] = mask[m_base + ms * 64 + nl];
    mk1[ms] = mask[m_base + ms * 64 + 32 + nl];
  }

  bf16x8 wgf[8], wpf[8];
#pragma unroll
  for (int kk = 0; kk < 8; ++kk) {
    wgf[kk] = *(const bf16x8*)(wgp + h * CD + kk * 16 + s * 8);
    wpf[kk] = *(const bf16x8*)(wpp + h * CD + kk * 16 + s * 8);
  }

  int rl = lane >> 4, p16 = lane & 15;
#define STAGE_ZNT(mt, bf)                                                   \
  {                                                                         \
    _Pragma("unroll")                                                       \
    for (int j = 0; j < 4; ++j) {                                           \
      int row = wvu * 16 + j * 4 + rl;                                      \
      int gc = (p16 ^ (row & 15)) << 3;                                     \
      gl16(zn + (size_t)((mt) + row) * CD + gc, &znt[bf][wvu * 16 + j * 4][0]); \
    }                                                                       \
  }

  asm volatile("" ::: "memory");
  STAGE_ZNT(m_base, 0);          // G0
  asm volatile("" ::: "memory");
  STAGE_ZNT(m_base + 64, 1);     // G1
  asm volatile("" ::: "memory");

  asm volatile("s_waitcnt lgkmcnt(0)" ::: "memory");  // bias ds_writes done

#define PROJ_ITER(ms, buf, WAITINSN)                                          \
  {                                                                           \
    asm volatile(WAITINSN ::: "memory");                                      \
    __builtin_amdgcn_s_barrier();                                             \
    asm volatile("" ::: "memory");                                            \
    f32x16 accg0, accg1, accp0, accp1;                                        \
    _Pragma("unroll")                                                         \
    for (int i = 0; i < 16; ++i) {                                            \
      accg0[i] = 0; accg1[i] = 0; accp0[i] = 0; accp1[i] = 0;                 \
    }                                                                         \
    _Pragma("unroll")                                                         \
    for (int kk = 0; kk < 8; ++kk) {                                          \
      int c = ((kk * 2 + s) ^ (nl & 15)) << 3;                                \
      bf16x8 zf0 = *(const bf16x8*)&znt[buf][nl][c];                          \
      bf16x8 zf1 = *(const bf16x8*)&znt[buf][32 + nl][c];                     \
      accg0 = __builtin_amdgcn_mfma_f32_32x32x16_bf16(wgf[kk], zf0, accg0, 0, 0, 0); \
      accg1 = __builtin_amdgcn_mfma_f32_32x32x16_bf16(wgf[kk], zf1, accg1, 0, 0, 0); \
      accp0 = __builtin_amdgcn_mfma_f32_32x32x16_bf16(wpf[kk], zf0, accp0, 0, 0, 0); \
      accp1 = __builtin_amdgcn_mfma_f32_32x32x16_bf16(wpf[kk], zf1, accp1, 0, 0, 0); \
    }                                                                         \
    int mt = m_base + (ms) * 64;                                              \
    _Pragma("unroll")                                                         \
    for (int r = 0; r < 16; ++r) {                                            \
      int hh = wvu * 32 + (r & 3) + 8 * (r >> 2) + 4 * s;                     \
      float bg = bsl[0][hh], bp = bsl[1][hh];                                 \
      u16* rowp = outp + (size_t)hh * MTOT + mt + nl;                         \
      rowp[0]  = f2bf(mk0[ms] * sigmoidf(accg0[r] + bg) * (accp0[r] + bp));   \
      rowp[32] = f2bf(mk1[ms] * sigmoidf(accg1[r] + bg) * (accp1[r] + bp));   \
    }                                                                         \
    asm volatile("" ::: "memory");                                            \
  }

  PROJ_ITER(0, 0, "s_waitcnt vmcnt(4)");    // awaits G0; G1 in flight
  PROJ_ITER(1, 1, "s_waitcnt vmcnt(32)");   // awaits G1; stores0 in flight
#undef PROJ_ITER
#undef STAGE_ZNT
}

// ---------------------------------------------------------------------------
// K3: triangle einsum. Per channel h: X_h = A_h * B_h^T (bf16 NT).
// 128x128 tile, BK=64. Counted-vmcnt pipeline; no stores mid-loop -> counts
// exact: 8 (next stage in flight) / 0 (last).
// XCD-aware remap (T1): each XCD gets 16 whole channels x 9 tiles; A_h+B_h
// (590KB) fits its 4MB L2 so the 3x panel re-reads hit L2.
// ---------------------------------------------------------------------------
__global__ __launch_bounds__(256) void k_tri(const u16* __restrict__ a,
                                             const u16* __restrict__ b,
                                             u16* __restrict__ x) {
  int n = blockIdx.x;
  int w = (n & 7) * 144 + (n >> 3);   // 1152 = 8 XCDs * 144
  int h = w / 9;
  int tile = w % 9;
  int tm = tile / 3, tn = tile % 3;
  int i0 = tm * 128, j0 = tn * 128;
  const u16* ah = a + (size_t)h * MTOT;
  const u16* bh = b + (size_t)h * MTOT;

  __shared__ u16 At[2][128][64];
  __shared__ u16 Bt[2][128][64];

  int lane = threadIdx.x & 63;
  int wvu = __builtin_amdgcn_readfirstlane(threadIdx.x >> 6);
  int nl = lane & 31, s = lane >> 5;
  int wr = wvu >> 1, wc = wvu & 1;
  int rl = lane >> 3, p8 = lane & 7;

  f32x16 acc[4];
#pragma unroll
  for (int q = 0; q < 4; ++q)
#pragma unroll
    for (int i = 0; i < 16; ++i) acc[q][i] = 0;

#define STAGE_TRI(bf, k0)                                                     \
  {                                                                           \
    _Pragma("unroll")                                                         \
    for (int j = 0; j < 4; ++j) {                                             \
      int row = wvu * 32 + j * 8 + rl;                                        \
      int gc = (p8 ^ (rl & 7)) << 3;                                          \
      gl16(ah + (size_t)(i0 + row) * NRES + (k0) + gc, &At[bf][wvu * 32 + j * 8][0]); \
      gl16(bh + (size_t)(j0 + row) * NRES + (k0) + gc, &Bt[bf][wvu * 32 + j * 8][0]); \
    }                                                                         \
  }

  asm volatile("" ::: "memory");
  STAGE_TRI(0, 0);        // G0 -> b0
  asm volatile("" ::: "memory");
  STAGE_TRI(1, 64);       // G1 -> b1
  asm volatile("" ::: "memory");

#define TRI_ITER(kb, WAITINSN, STAGEIT)                                       \
  {                                                                           \
    const int cur = (kb) & 1;                                                 \
    asm volatile(WAITINSN ::: "memory");                                      \
    __builtin_amdgcn_s_barrier();                                             \
    asm volatile("" ::: "memory");                                            \
    _Pragma("unroll")                                                         \
    for (int kk = 0; kk < 4; ++kk) {                                          \
      int c = ((kk * 2 + s) ^ (nl & 7)) << 3;                                 \
      bf16x8 af0 = *(const bf16x8*)&At[cur][wr * 64 + nl][c];                 \
      bf16x8 af1 = *(const bf16x8*)&At[cur][wr * 64 + 32 + nl][c];            \
      bf16x8 bf0 = *(const bf16x8*)&Bt[cur][wc * 64 + nl][c];                 \
      bf16x8 bf1 = *(const bf16x8*)&Bt[cur][wc * 64 + 32 + nl][c];            \
      acc[0] = __builtin_amdgcn_mfma_f32_32x32x16_bf16(af0, bf0, acc[0], 0, 0, 0); \
      acc[1] = __builtin_amdgcn_mfma_f32_32x32x16_bf16(af0, bf1, acc[1], 0, 0, 0); \
      acc[2] = __builtin_amdgcn_mfma_f32_32x32x16_bf16(af1, bf0, acc[2], 0, 0, 0); \
      acc[3] = __builtin_amdgcn_mfma_f32_32x32x16_bf16(af1, bf1, acc[3], 0, 0, 0); \
    }                                                                         \
    asm volatile("s_waitcnt lgkmcnt(0)" ::: "memory");                        \
    if (STAGEIT) {                                                            \
      __builtin_amdgcn_s_barrier();   /* buffer reads done; drain-free */     \
      asm volatile("" ::: "memory");                                          \
      STAGE_TRI(cur, ((kb) + 2) * 64);                                        \
      asm volatile("" ::: "memory");                                          \
    }                                                                         \
  }

  TRI_ITER(0, "s_waitcnt vmcnt(8)", 1);   // awaits G0; G1 in flight; G2->b0
  TRI_ITER(1, "s_waitcnt vmcnt(8)", 1);   // awaits G1; G2 in flight; G3->b1
  TRI_ITER(2, "s_waitcnt vmcnt(8)", 1);   // awaits G2; G3 in flight; G4->b0
  TRI_ITER(3, "s_waitcnt vmcnt(8)", 1);   // awaits G3; G4 in flight; G5->b1
  TRI_ITER(4, "s_waitcnt vmcnt(8)", 0);   // awaits G4; G5 in flight
  TRI_ITER(5, "s_waitcnt vmcnt(0)", 0);   // awaits G5 (last)
#undef TRI_ITER
#undef STAGE_TRI

  u16* xh = x + (size_t)h * MTOT;
#pragma unroll
  for (int msub = 0; msub < 2; ++msub)
#pragma unroll
    for (int nsub = 0; nsub < 2; ++nsub) {
      int j = j0 + wc * 64 + nsub * 32 + nl;
#pragma unroll
      for (int r = 0; r < 16; ++r) {
        int i = i0 + wr * 64 + msub * 32 + (r & 3) + 8 * (r >> 2) + 4 * s;
        xh[(size_t)i * NRES + j] = f2bf(acc[msub * 2 + nsub][r]);
      }
    }
}

// ---------------------------------------------------------------------------
// K4: out[m][o] = sigmoid(zn.g_w^T + g_b)[m][o]
//               * ( rs[m]*(x.W'^T)[m][o] - rs[m]*mu[m]*c1[o] + c2[o] )
// LN folded algebraically (W' = ln_out_w (.) z_w, c1/c2 precomputed):
// no normalize write-back pass, GEMM runs on the RAW transposed x tile.
// Load-order discipline: zn loads -> gwf/gb -> x prefetch; lgkm-only raw
// barriers. vmcnt retires in order, so the zn/gwf waits never drain the
// younger x loads -> x HBM latency hides under the gate GEMM (T14).
// ---------------------------------------------------------------------------
__global__ __launch_bounds__(256) void k_out(
    const u16* __restrict__ x, const u16* __restrict__ zn,
    const u16* __restrict__ wb, const float* __restrict__ gb,
    const float2* __restrict__ c12, float* __restrict__ out) {
  int m0 = blockIdx.x * 64;
  int t = threadIdx.x;
  int wv = t >> 6, lane = t & 63, nl = lane & 31, s = lane >> 5;
  int o = wv * 32 + nl;

  __shared__ u16 tile[64][136];
  __shared__ float2 stat[64];   // {rs, rs*mu} per m-row

  const u16* gwp = wb + 4 * 16384;   // g_w
  const u16* zwp = wb + 5 * 16384;   // W' = z_w with ln_out_w folded

  // ---- issue order: zn(oldest) -> gwf,gb -> x(youngest)
  uint4 znv[4];
#pragma unroll
  for (int it = 0; it < 4; ++it) {
    int idx = it * 256 + t, r = idx >> 4, c8 = idx & 15;
    znv[it] = *(const uint4*)(zn + (size_t)(m0 + r) * CD + c8 * 8);
  }
  bf16x8 gwf[8];
#pragma unroll
  for (int kk = 0; kk < 8; ++kk)
    gwf[kk] = *(const bf16x8*)(gwp + o * CD + kk * 16 + s * 8);
  float gbv = gb[o];

  int mc = t & 7;
  uint4 xv0[2], xv1[2];
#pragma unroll
  for (int ps = 0; ps < 2; ++ps) {
    int hp = (ps * 256 + t) >> 3;
    xv0[ps] = *(const uint4*)(x + (size_t)(2 * hp)     * MTOT + m0 + mc * 8);
    xv1[ps] = *(const uint4*)(x + (size_t)(2 * hp + 1) * MTOT + m0 + mc * 8);
  }

  // stage zn -> tile (waits only zn; x stays in flight)
#pragma unroll
  for (int it = 0; it < 4; ++it) {
    int idx = it * 256 + t, r = idx >> 4, c8 = idx & 15;
    *(uint4*)&tile[r][c8 * 8] = znv[it];
  }
  asm volatile("s_waitcnt lgkmcnt(0)" ::: "memory");
  __builtin_amdgcn_s_barrier();

  // ---- phase A: gate GEMM (C[m][o])
  f32x16 gacc[2];
#pragma unroll
  for (int i = 0; i < 16; ++i) { gacc[0][i] = 0; gacc[1][i] = 0; }
#pragma unroll
  for (int kk = 0; kk < 8; ++kk) {
    bf16x8 zf0 = *(const bf16x8*)&tile[nl][kk * 16 + s * 8];
    bf16x8 zf1 = *(const bf16x8*)&tile[32 + nl][kk * 16 + s * 8];
    gacc[0] = __builtin_amdgcn_mfma_f32_32x32x16_bf16(zf0, gwf[kk], gacc[0], 0, 0, 0);
    gacc[1] = __builtin_amdgcn_mfma_f32_32x32x16_bf16(zf1, gwf[kk], gacc[1], 0, 0, 0);
  }
  float gv[32];
#pragma unroll
  for (int ms = 0; ms < 2; ++ms)
#pragma unroll
    for (int r = 0; r < 16; ++r)
      gv[ms * 16 + r] = sigmoidf(gacc[ms][r] + gbv);
  asm volatile("s_waitcnt lgkmcnt(0)" ::: "memory");
  __builtin_amdgcn_s_barrier();   // all waves done reading zn tile

  // W' fragments (younger than x; x-waits below don't drain these)
  bf16x8 zwf[8];
#pragma unroll
  for (int kk = 0; kk < 8; ++kk)
    zwf[kk] = *(const bf16x8*)(zwp + o * CD + kk * 16 + s * 8);

  // ---- phase B: transpose x[h][m] -> tile[m][h] (consumes prefetched regs)
#pragma unroll
  for (int ps = 0; ps < 2; ++ps) {
    int hp = (ps * 256 + t) >> 3;
    unsigned c0[4] = {xv0[ps].x, xv0[ps].y, xv0[ps].z, xv0[ps].w};
    unsigned c1[4] = {xv1[ps].x, xv1[ps].y, xv1[ps].z, xv1[ps].w};
#pragma unroll
    for (int q = 0; q < 4; ++q) {
      ushort2 lo, hi;
      lo.x = (u16)(c0[q] & 0xffffu); lo.y = (u16)(c1[q] & 0xffffu);
      hi.x = (u16)(c0[q] >> 16);     hi.y = (u16)(c1[q] >> 16);
      *(ushort2*)&tile[mc * 8 + 2 * q][2 * hp]     = lo;
      *(ushort2*)&tile[mc * 8 + 2 * q + 1][2 * hp] = hi;
    }
  }
  asm volatile("s_waitcnt lgkmcnt(0)" ::: "memory");
  __builtin_amdgcn_s_barrier();

  // ---- stats: one-pass mean/var per m-row (4x b128 reads, no write-back)
  {
    int r = t >> 2, q = t & 3;
    float sum = 0.0f, sq = 0.0f;
#pragma unroll
    for (int i = 0; i < 4; ++i) {
      uint4 v = *(const uint4*)&tile[r][q * 32 + i * 8];
      unsigned cc[4] = {v.x, v.y, v.z, v.w};
#pragma unroll
      for (int j = 0; j < 4; ++j) {
        float a = bf2f((u16)(cc[j] & 0xffffu));
        float b = bf2f((u16)(cc[j] >> 16));
        sum += a + b; sq += a * a + b * b;
      }
    }
    sum += __shfl_xor(sum, 1); sum += __shfl_xor(sum, 2);
    sq  += __shfl_xor(sq, 1);  sq  += __shfl_xor(sq, 2);
    float mu = sum * (1.0f / CD);
    float var = sq * (1.0f / CD) - mu * mu;
    float rs = rsqrtf(var + 1e-5f);
    if (q == 0) stat[r] = make_float2(rs, rs * mu);
  }

  // ---- W' GEMM on the raw x tile (reads only; no barrier needed vs stats)
  f32x16 acc[2];
#pragma unroll
  for (int i = 0; i < 16; ++i) { acc[0][i] = 0; acc[1][i] = 0; }
#pragma unroll
  for (int kk = 0; kk < 8; ++kk) {
    bf16x8 af0 = *(const bf16x8*)&tile[nl][kk * 16 + s * 8];
    bf16x8 af1 = *(const bf16x8*)&tile[32 + nl][kk * 16 + s * 8];
    acc[0] = __builtin_amdgcn_mfma_f32_32x32x16_bf16(af0, zwf[kk], acc[0], 0, 0, 0);
    acc[1] = __builtin_amdgcn_mfma_f32_32x32x16_bf16(af1, zwf[kk], acc[1], 0, 0, 0);
  }
  asm volatile("s_waitcnt lgkmcnt(0)" ::: "memory");
  __builtin_amdgcn_s_barrier();   // stat[] visible to all

  float2 cc2 = c12[o];
#pragma unroll
  for (int ms = 0; ms < 2; ++ms)
#pragma unroll
    for (int rr = 0; rr < 16; ++rr) {
      int rowoff = (rr & 3) + 8 * (rr >> 2) + 4 * s;
      int row = ms * 32 + rowoff;
      float2 st = stat[row];
      out[(size_t)(m0 + row) * CD + o] =
          gv[ms * 16 + rr] * (st.x * acc[ms][rr] - st.y * cc2.x + cc2.y);
    }
}

// ---------------------------------------------------------------------------
extern "C" void kernel_launch(void* const* d_in, const int* in_sizes, int n_in,
                              void* d_out, int out_size, void* d_ws, size_t ws_size,
                              hipStream_t stream) {
  const float* z       = (const float*)d_in[0];
  const float* mask    = (const float*)d_in[1];
  const float* ln_in_w = (const float*)d_in[2];
  const float* ln_in_b = (const float*)d_in[3];
  const float* a_g_w   = (const float*)d_in[4];
  const float* a_g_b   = (const float*)d_in[5];
  const float* a_p_w   = (const float*)d_in[6];
  const float* a_p_b   = (const float*)d_in[7];
  const float* b_g_w   = (const float*)d_in[8];
  const float* b_g_b   = (const float*)d_in[9];
  const float* b_p_w   = (const float*)d_in[10];
  const float* b_p_b   = (const float*)d_in[11];
  const float* g_w     = (const float*)d_in[12];
  const float* g_b     = (const float*)d_in[13];
  const float* ln_o_w  = (const float*)d_in[14];
  const float* ln_o_b  = (const float*)d_in[15];
  const float* z_w     = (const float*)d_in[16];
  const float* z_b     = (const float*)d_in[17];
  float* out = (float*)d_out;

  const size_t SZ = (size_t)MTOT * CD * sizeof(u16);
  char* w = (char*)d_ws;
  u16* zn = (u16*)(w);              // live until k_out
  u16* a  = (u16*)(w + SZ);
  u16* b  = (u16*)(w + 2 * SZ);
  u16* x  = (u16*)(w + 3 * SZ);
  u16* wb = (u16*)(w + 4 * SZ);
  float2* c12 = (float2*)(w + 4 * SZ + 6 * 16384 * sizeof(u16));
  (void)ws_size; (void)in_sizes; (void)n_in; (void)out_size;

  k_prep<<<PREP_BLOCKS, 256, 0, stream>>>(
      z, ln_in_w, ln_in_b, zn,
      a_g_w, a_p_w, b_g_w, b_p_w, g_w, z_w,
      ln_o_w, ln_o_b, z_b, wb, c12);
  k_proj<<<2304, 256, 0, stream>>>(zn, mask, wb,
      a_g_b, a_p_b, b_g_b, b_p_b, a, b);
  k_tri<<<1152, 256, 0, stream>>>(a, b, x);
  k_out<<<MTOT / 64, 256, 0, stream>>>(x, zn, wb, g_b, c12, out);
}